// Round 1
// baseline (640.704 us; speedup 1.0000x reference)
//
#include <hip/hip_runtime.h>

#define NN 32768      // total nodes
#define NP 512        // nodes per graph
#define NB 64         // graphs
#define NE 1048576    // edges
#define FIN 16
#define H 128
#define BN_EPS 1e-5f

// ---------------- workspace layout (bytes) ----------------
static constexpr size_t SZ_BUF   = (size_t)NN * H * 4;          // 16 MiB
static constexpr size_t OFF_BUFA = 0;
static constexpr size_t OFF_BUFB = OFF_BUFA + SZ_BUF;
static constexpr size_t OFF_SSRC = OFF_BUFB + SZ_BUF;           // E ints (sorted src)
static constexpr size_t OFF_SW   = OFF_SSRC + (size_t)NE * 4;   // E floats (sorted w)
static constexpr size_t OFF_OFFS = OFF_SW + (size_t)NE * 4;     // N+1 ints
static constexpr size_t OFF_CURS = OFF_OFFS + ((size_t)NN + 64) * 4;
// --- zeroed region (one memset) ---
static constexpr size_t OFF_ZERO = OFF_CURS + (size_t)NN * 4;
static constexpr size_t OFF_CNT   = OFF_ZERO;                    // N ints
static constexpr size_t OFF_DFLAT = OFF_CNT + (size_t)NN * 4;    // N f32
static constexpr size_t OFF_NUM   = OFF_DFLAT + (size_t)NN * 4;  // NB f32
static constexpr size_t OFF_BN    = OFF_NUM + NB * 4;            // 4*H f32 (sum1,sq1,sum2,sq2)
static constexpr size_t OFF_POOL  = OFF_BN + 4 * H * 4;          // NB*2*H f32
static constexpr size_t ZERO_BYTES = (OFF_POOL + (size_t)NB * 2 * H * 4) - OFF_ZERO;
// --- end zero region ---
static constexpr size_t OFF_S    = OFF_POOL + (size_t)NB * 2 * H * 4;  // N*2 f32
static constexpr size_t OFF_SCSH = OFF_S + (size_t)NN * 2 * 4;         // 4*H f32 (scale/shift x2)
static constexpr size_t OFF_GST  = OFF_SCSH + 4 * H * 4;               // 4*NB f32 (den,ss00,ss01,ss11)

// ---------------- kernels ----------------

// x0 = node_feature @ W_pre + b_pre   (8 nodes per 128-thread block)
__global__ void k_pre(const float* __restrict__ nf, const float* __restrict__ Wp,
                      const float* __restrict__ bp, float* __restrict__ x0) {
    __shared__ float sW[FIN * H];
    __shared__ float sNF[8 * FIN];
    int tid = threadIdx.x;
    for (int i = tid; i < FIN * H; i += 128) sW[i] = Wp[i];
    int n0 = blockIdx.x * 8;
    sNF[tid] = nf[n0 * FIN + tid];
    __syncthreads();
    float b = bp[tid];
    #pragma unroll
    for (int r = 0; r < 8; ++r) {
        float acc = b;
        #pragma unroll
        for (int f = 0; f < FIN; ++f) acc += sNF[r * FIN + f] * sW[f * H + tid];
        x0[(size_t)(n0 + r) * H + tid] = acc;
    }
}

__global__ void k_count(const int* __restrict__ dst, int* __restrict__ cnt) {
    int e = blockIdx.x * 256 + threadIdx.x;
    if (e < NE) atomicAdd(&cnt[dst[e]], 1);
}

// single block of 1024 threads: exclusive scan of 32768 counts
__global__ void k_scan(const int* __restrict__ cnt, int* __restrict__ offs,
                       int* __restrict__ curs) {
    __shared__ int sd[1024];
    int t = threadIdx.x;
    int base = t * 32;
    int s = 0;
    #pragma unroll
    for (int i = 0; i < 32; ++i) s += cnt[base + i];
    sd[t] = s;
    __syncthreads();
    for (int off = 1; off < 1024; off <<= 1) {
        int v = (t >= off) ? sd[t - off] : 0;
        __syncthreads();
        sd[t] += v;
        __syncthreads();
    }
    int run = sd[t] - s;  // exclusive prefix
    for (int i = 0; i < 32; ++i) {
        int c = cnt[base + i];
        offs[base + i] = run;
        curs[base + i] = run;
        run += c;
    }
    if (t == 1023) offs[NN] = run;  // == NE
}

__global__ void k_scatter(const int* __restrict__ src, const int* __restrict__ dst,
                          const float* __restrict__ ew, int* __restrict__ curs,
                          int* __restrict__ ssrc, float* __restrict__ sw) {
    int e = blockIdx.x * 256 + threadIdx.x;
    if (e < NE) {
        int d = dst[e];
        int p = atomicAdd(&curs[d], 1);
        ssrc[p] = src[e];
        sw[p] = ew[e];
    }
}

// agg[node,h] = sum_{e in CSR[node]} w_e * x[src_e, h]    (block = 1 node, 128 threads)
__global__ void k_agg(const float* __restrict__ x, const int* __restrict__ offs,
                      const int* __restrict__ ssrc, const float* __restrict__ sw,
                      float* __restrict__ agg) {
    int bid = blockIdx.x;
    int node = (bid & 7) * (NN / 8) + (bid >> 3);  // XCD-locality swizzle: 8 graphs per XCD
    int h = threadIdx.x;
    int beg = offs[node], end = offs[node + 1];
    float acc = 0.f;
    int j = beg;
    for (; j + 4 <= end; j += 4) {
        int s0 = ssrc[j], s1 = ssrc[j + 1], s2 = ssrc[j + 2], s3 = ssrc[j + 3];
        float w0 = sw[j], w1 = sw[j + 1], w2 = sw[j + 2], w3 = sw[j + 3];
        float v0 = x[(size_t)s0 * H + h], v1 = x[(size_t)s1 * H + h];
        float v2 = x[(size_t)s2 * H + h], v3 = x[(size_t)s3 * H + h];
        acc += w0 * v0;
        acc += w1 * v1;
        acc += w2 * v2;
        acc += w3 * v3;
    }
    for (; j < end; ++j) acc += sw[j] * x[(size_t)ssrc[j] * H + h];
    agg[(size_t)node * H + h] = acc;
}

// Y = Amat@Wrel + Xmat@Wroot + brel ; fused BN column-stat partials.
// Block: 64 rows x 128 cols, 256 threads, 8x4 per-thread tile. Y may alias Amat.
__global__ __launch_bounds__(256) void k_gemm(
        const float* Amat, const float* __restrict__ Xmat,
        const float* __restrict__ Wrel, const float* __restrict__ Wroot,
        const float* __restrict__ brel, float* Y,
        float* __restrict__ bn_sum, float* __restrict__ bn_sq) {
    __shared__ float At[32][64];    // A tile transposed [k][row]
    __shared__ float Wt[32][128];   // W tile [k][col]
    __shared__ float colS[128], colQ[128];
    int tid = threadIdx.x;
    int tc = tid & 31;   // col group (4 cols)
    int tr = tid >> 5;   // row group (8 rows)
    int row0 = blockIdx.x * 64;
    float acc[8][4];
    #pragma unroll
    for (int r = 0; r < 8; ++r)
        #pragma unroll
        for (int c = 0; c < 4; ++c) acc[r][c] = 0.f;

    int lr = tid & 63;    // A-load row
    int lkb = tid >> 6;   // A-load k base (0..3)
    int lc = tid & 127;   // W-load col
    int lkb2 = tid >> 7;  // W-load k base (0..1)

    for (int m = 0; m < 2; ++m) {
        const float* A = m ? Xmat : Amat;
        const float* __restrict__ W = m ? Wroot : Wrel;
        for (int k0 = 0; k0 < H; k0 += 32) {
            __syncthreads();
            #pragma unroll
            for (int i = 0; i < 8; ++i) {
                int kk = lkb + 4 * i;
                At[kk][lr] = A[(size_t)(row0 + lr) * H + k0 + kk];
            }
            #pragma unroll
            for (int i = 0; i < 16; ++i) {
                int kk = lkb2 + 2 * i;
                Wt[kk][lc] = W[(size_t)(k0 + kk) * H + lc];
            }
            __syncthreads();
            #pragma unroll
            for (int k = 0; k < 32; ++k) {
                float4 w4 = *(const float4*)&Wt[k][tc * 4];
                float4 a0 = *(const float4*)&At[k][tr * 8];
                float4 a1 = *(const float4*)&At[k][tr * 8 + 4];
                float av[8] = {a0.x, a0.y, a0.z, a0.w, a1.x, a1.y, a1.z, a1.w};
                float wv[4] = {w4.x, w4.y, w4.z, w4.w};
                #pragma unroll
                for (int r = 0; r < 8; ++r)
                    #pragma unroll
                    for (int c = 0; c < 4; ++c) acc[r][c] += av[r] * wv[c];
            }
        }
    }
    // epilogue: bias, store, BN partials
    float bb[4];
    #pragma unroll
    for (int c = 0; c < 4; ++c) bb[c] = brel[tc * 4 + c];
    float ls[4] = {0, 0, 0, 0}, lq[4] = {0, 0, 0, 0};
    #pragma unroll
    for (int r = 0; r < 8; ++r) {
        int row = row0 + tr * 8 + r;
        float v0 = acc[r][0] + bb[0], v1 = acc[r][1] + bb[1];
        float v2 = acc[r][2] + bb[2], v3 = acc[r][3] + bb[3];
        float4 o; o.x = v0; o.y = v1; o.z = v2; o.w = v3;
        *(float4*)&Y[(size_t)row * H + tc * 4] = o;
        ls[0] += v0; lq[0] += v0 * v0;
        ls[1] += v1; lq[1] += v1 * v1;
        ls[2] += v2; lq[2] += v2 * v2;
        ls[3] += v3; lq[3] += v3 * v3;
    }
    __syncthreads();
    if (tid < 128) { colS[tid] = 0.f; colQ[tid] = 0.f; }
    __syncthreads();
    #pragma unroll
    for (int c = 0; c < 4; ++c) {
        atomicAdd(&colS[tc * 4 + c], ls[c]);
        atomicAdd(&colQ[tc * 4 + c], lq[c]);
    }
    __syncthreads();
    if (tid < 128) {
        atomicAdd(&bn_sum[tid], colS[tid]);
        atomicAdd(&bn_sq[tid], colQ[tid]);
    }
}

// finalize BN: scale = rsqrt(var+eps)*g ; shift = be - mu*scale
__global__ void k_bnfinal(const float* __restrict__ bn_sum, const float* __restrict__ bn_sq,
                          const float* __restrict__ g, const float* __restrict__ be,
                          float* __restrict__ sc_sh) {
    int t = threadIdx.x;
    float mu = bn_sum[t] * (1.f / NN);
    float var = bn_sq[t] * (1.f / NN) - mu * mu;
    float sc = rsqrtf(var + BN_EPS) * g[t];
    sc_sh[t] = sc;
    sc_sh[H + t] = be[t] - mu * sc;
}

// in-place x = relu(y*scale + shift), float4
__global__ void k_bnrelu(float* __restrict__ y, const float* __restrict__ sc_sh) {
    int idx = blockIdx.x * 256 + threadIdx.x;
    int c = (idx & 31) * 4;
    float4 v = ((const float4*)y)[idx];
    float4 sc = *(const float4*)&sc_sh[c];
    float4 sh = *(const float4*)&sc_sh[H + c];
    v.x = fmaxf(fmaf(v.x, sc.x, sh.x), 0.f);
    v.y = fmaxf(fmaf(v.y, sc.y, sh.y), 0.f);
    v.z = fmaxf(fmaf(v.z, sc.z, sh.z), 0.f);
    v.w = fmaxf(fmaf(v.w, sc.w, sh.w), 0.f);
    ((float4*)y)[idx] = v;
}

// s = softmax(x @ W_pool + b_pool): one wave per node
__global__ void k_pool_s(const float* __restrict__ x, const float* __restrict__ Wp,
                         const float* __restrict__ bp, float* __restrict__ s) {
    int tid = threadIdx.x;
    int lane = tid & 63, wv = tid >> 6;
    int n = blockIdx.x * 4 + wv;
    const float* xr = x + (size_t)n * H;
    float x0 = xr[lane], x1 = xr[lane + 64];
    float z0 = x0 * Wp[lane * 2] + x1 * Wp[(lane + 64) * 2];
    float z1 = x0 * Wp[lane * 2 + 1] + x1 * Wp[(lane + 64) * 2 + 1];
    for (int o = 32; o; o >>= 1) { z0 += __shfl_down(z0, o); z1 += __shfl_down(z1, o); }
    if (lane == 0) {
        z0 += bp[0]; z1 += bp[1];
        float m = fmaxf(z0, z1);
        float e0 = expf(z0 - m), e1 = expf(z1 - m);
        float inv = 1.f / (e0 + e1);
        s[n * 2] = e0 * inv;
        s[n * 2 + 1] = e1 * inv;
    }
}

// pool[b,k,h] += sum_n s[n,k]*x[n,h]   (block = 64-node chunk of one graph)
__global__ void k_pool_out(const float* __restrict__ x, const float* __restrict__ s,
                           float* __restrict__ pool) {
    int b = blockIdx.x & 63, chunk = blockIdx.x >> 6;
    int h = threadIdx.x;
    float a0 = 0.f, a1 = 0.f;
    int n0 = b * NP + chunk * 64;
    for (int i = 0; i < 64; ++i) {
        float2 sv = ((const float2*)s)[n0 + i];
        float xv = x[(size_t)(n0 + i) * H + h];
        a0 += sv.x * xv;
        a1 += sv.y * xv;
    }
    atomicAdd(&pool[(b * 2 + 0) * H + h], a0);
    atomicAdd(&pool[(b * 2 + 1) * H + h], a1);
}

// per-edge: d_flat[src] += w ; num[graph] += w*<s[src],s[dst]>
__global__ void k_edge_stats(const int* __restrict__ src, const int* __restrict__ dst,
                             const float* __restrict__ ew, const float* __restrict__ s,
                             float* __restrict__ dflat, float* __restrict__ num) {
    __shared__ float ln[NB];
    int t = threadIdx.x;
    if (t < NB) ln[t] = 0.f;
    __syncthreads();
    int e = blockIdx.x * 256 + t;
    if (e < NE) {
        int a = src[e], d = dst[e];
        float w = ew[e];
        atomicAdd(&dflat[a], w);
        float2 sa = ((const float2*)s)[a];
        float2 sd = ((const float2*)s)[d];
        float c = w * (sa.x * sd.x + sa.y * sd.y);
        atomicAdd(&ln[a >> 9], c);
    }
    __syncthreads();
    if (t < NB) {
        float v = ln[t];
        if (v != 0.f) atomicAdd(&num[t], v);
    }
}

// per-graph node sums: den, ss00, ss01, ss11
__global__ void k_graph_stats(const float* __restrict__ s, const float* __restrict__ dflat,
                              float* __restrict__ gst) {
    int b = blockIdx.x;
    int t = threadIdx.x;  // 128
    float den = 0.f, p00 = 0.f, p01 = 0.f, p11 = 0.f;
    for (int i = t; i < NP; i += 128) {
        int n = b * NP + i;
        float2 sv = ((const float2*)s)[n];
        float d = dflat[n];
        den += d * (sv.x * sv.x + sv.y * sv.y);
        p00 += sv.x * sv.x;
        p01 += sv.x * sv.y;
        p11 += sv.y * sv.y;
    }
    for (int o = 32; o; o >>= 1) {
        den += __shfl_down(den, o); p00 += __shfl_down(p00, o);
        p01 += __shfl_down(p01, o); p11 += __shfl_down(p11, o);
    }
    __shared__ float tmp[4][2];
    if ((t & 63) == 0) {
        int w = t >> 6;
        tmp[0][w] = den; tmp[1][w] = p00; tmp[2][w] = p01; tmp[3][w] = p11;
    }
    __syncthreads();
    if (t == 0) {
        gst[b] = tmp[0][0] + tmp[0][1];
        gst[NB + b] = tmp[1][0] + tmp[1][1];
        gst[2 * NB + b] = tmp[2][0] + tmp[2][1];
        gst[3 * NB + b] = tmp[3][0] + tmp[3][1];
    }
}

// logits[b,:] = relu(pool[b]).flatten @ W_post + b_post
__global__ void k_logits(const float* __restrict__ pool, const float* __restrict__ Wpost,
                         const float* __restrict__ bpost, float* __restrict__ out) {
    int b = blockIdx.x, t = threadIdx.x;  // 256
    float v = pool[b * 256 + t];
    v = v > 0.f ? v : 0.f;
    float p0 = v * Wpost[t * 2], p1 = v * Wpost[t * 2 + 1];
    for (int o = 32; o; o >>= 1) { p0 += __shfl_down(p0, o); p1 += __shfl_down(p1, o); }
    __shared__ float t0[4], t1[4];
    if ((t & 63) == 0) { t0[t >> 6] = p0; t1[t >> 6] = p1; }
    __syncthreads();
    if (t == 0) {
        out[b * 2] = t0[0] + t0[1] + t0[2] + t0[3] + bpost[0];
        out[b * 2 + 1] = t1[0] + t1[1] + t1[2] + t1[3] + bpost[1];
    }
}

__global__ void k_losses(const float* __restrict__ num, const float* __restrict__ gst,
                         float* __restrict__ out) {
    int t = threadIdx.x;  // 64 = 1 wave
    float den = gst[t], s00 = gst[NB + t], s01 = gst[2 * NB + t], s11 = gst[3 * NB + t];
    float mc = -(num[t] / den);
    float nrm = sqrtf(s00 * s00 + 2.f * s01 * s01 + s11 * s11);
    const float a = 0.70710678118654752440f;  // 1/sqrt(2)
    float d00 = s00 / nrm - a, d01 = s01 / nrm, d11 = s11 / nrm - a;
    float ol = sqrtf(d00 * d00 + 2.f * d01 * d01 + d11 * d11);
    for (int o = 32; o; o >>= 1) { mc += __shfl_down(mc, o); ol += __shfl_down(ol, o); }
    if (t == 0) {
        out[NB * 2] = mc * (1.f / NB);
        out[NB * 2 + 1] = ol * (1.f / NB);
    }
}

// ---------------- launch ----------------
extern "C" void kernel_launch(void* const* d_in, const int* in_sizes, int n_in,
                              void* d_out, int out_size, void* d_ws, size_t ws_size,
                              hipStream_t stream) {
    const float* nf     = (const float*)d_in[0];
    const int*   ei     = (const int*)d_in[1];
    const float* ew     = (const float*)d_in[2];
    const float* W_pre  = (const float*)d_in[4];
    const float* b_pre  = (const float*)d_in[5];
    const float* W1_rel = (const float*)d_in[6];
    const float* b1_rel = (const float*)d_in[7];
    const float* W1_root= (const float*)d_in[8];
    const float* g1     = (const float*)d_in[9];
    const float* be1    = (const float*)d_in[10];
    const float* W2_rel = (const float*)d_in[11];
    const float* b2_rel = (const float*)d_in[12];
    const float* W2_root= (const float*)d_in[13];
    const float* g2     = (const float*)d_in[14];
    const float* be2    = (const float*)d_in[15];
    const float* W_pool = (const float*)d_in[16];
    const float* b_pool = (const float*)d_in[17];
    const float* W_post = (const float*)d_in[18];
    const float* b_post = (const float*)d_in[19];

    char* ws = (char*)d_ws;
    float* bufA  = (float*)(ws + OFF_BUFA);
    float* bufB  = (float*)(ws + OFF_BUFB);
    int*   ssrc  = (int*)(ws + OFF_SSRC);
    float* sw    = (float*)(ws + OFF_SW);
    int*   offs  = (int*)(ws + OFF_OFFS);
    int*   curs  = (int*)(ws + OFF_CURS);
    int*   cnt   = (int*)(ws + OFF_CNT);
    float* dflat = (float*)(ws + OFF_DFLAT);
    float* numA  = (float*)(ws + OFF_NUM);
    float* bn    = (float*)(ws + OFF_BN);
    float* pool  = (float*)(ws + OFF_POOL);
    float* sarr  = (float*)(ws + OFF_S);
    float* scsh  = (float*)(ws + OFF_SCSH);
    float* gst   = (float*)(ws + OFF_GST);
    float* outF  = (float*)d_out;

    const int* srcA = ei;
    const int* dstA = ei + NE;

    hipMemsetAsync(ws + OFF_ZERO, 0, ZERO_BYTES, stream);

    k_pre<<<NN / 8, 128, 0, stream>>>(nf, W_pre, b_pre, bufA);
    k_count<<<NE / 256, 256, 0, stream>>>(dstA, cnt);
    k_scan<<<1, 1024, 0, stream>>>(cnt, offs, curs);
    k_scatter<<<NE / 256, 256, 0, stream>>>(srcA, dstA, ew, curs, ssrc, sw);

    // layer 1
    k_agg<<<NN, 128, 0, stream>>>(bufA, offs, ssrc, sw, bufB);
    k_gemm<<<NN / 64, 256, 0, stream>>>(bufB, bufA, W1_rel, W1_root, b1_rel, bufB,
                                        bn, bn + H);
    k_bnfinal<<<1, H, 0, stream>>>(bn, bn + H, g1, be1, scsh);
    k_bnrelu<<<(NN * H / 4) / 256, 256, 0, stream>>>(bufB, scsh);

    // layer 2
    k_agg<<<NN, 128, 0, stream>>>(bufB, offs, ssrc, sw, bufA);
    k_gemm<<<NN / 64, 256, 0, stream>>>(bufA, bufB, W2_rel, W2_root, b2_rel, bufA,
                                        bn + 2 * H, bn + 3 * H);
    k_bnfinal<<<1, H, 0, stream>>>(bn + 2 * H, bn + 3 * H, g2, be2, scsh + 2 * H);
    k_bnrelu<<<(NN * H / 4) / 256, 256, 0, stream>>>(bufA, scsh + 2 * H);

    // pooling + losses
    k_pool_s<<<NN / 4, 256, 0, stream>>>(bufA, W_pool, b_pool, sarr);
    k_pool_out<<<8 * NB, 128, 0, stream>>>(bufA, sarr, pool);
    k_edge_stats<<<NE / 256, 256, 0, stream>>>(srcA, dstA, ew, sarr, dflat, numA);
    k_graph_stats<<<NB, 128, 0, stream>>>(sarr, dflat, gst);
    k_logits<<<NB, 256, 0, stream>>>(pool, W_post, b_post, outF);
    k_losses<<<1, 64, 0, stream>>>(numA, gst, outF);
}

// Round 2
// 480.553 us; speedup vs baseline: 1.3333x; 1.3333x over previous
//
#include <hip/hip_runtime.h>

#define NN 32768      // total nodes
#define NP 512        // nodes per graph
#define NB 64         // graphs
#define NE 1048576    // edges
#define FIN 16
#define H 128
#define BN_EPS 1e-5f
#define EB 256        // edge_stats grid blocks

// ---------------- workspace layout (bytes) ----------------
static constexpr size_t SZ_BUF   = (size_t)NN * H * 4;          // 16 MiB
static constexpr size_t OFF_BUFA = 0;
static constexpr size_t OFF_BUFB = OFF_BUFA + SZ_BUF;
static constexpr size_t OFF_SSRC = OFF_BUFB + SZ_BUF;           // E ints (sorted src)
static constexpr size_t OFF_SW   = OFF_SSRC + (size_t)NE * 4;   // E floats (sorted w)
static constexpr size_t OFF_OFFS = OFF_SW + (size_t)NE * 4;     // N+1 ints
static constexpr size_t OFF_CURS = OFF_OFFS + ((size_t)NN + 64) * 4;
// --- zeroed region (one memset) ---
static constexpr size_t OFF_ZERO = OFF_CURS + (size_t)NN * 4;
static constexpr size_t OFF_CNT  = OFF_ZERO;                     // NN ints
static constexpr size_t OFF_BN   = OFF_CNT + (size_t)NN * 4;     // 2 layers * 8 shadows * 2 * H f32
static constexpr size_t SZ_BNL   = (size_t)8 * 2 * H * 4;        // per-layer bytes
static constexpr size_t OFF_POOL = OFF_BN + 2 * SZ_BNL;          // NB*2*H f32
static constexpr size_t ZERO_BYTES = (OFF_POOL + (size_t)NB * 2 * H * 4) - OFF_ZERO;
// --- end zero region ---
static constexpr size_t OFF_S    = OFF_POOL + (size_t)NB * 2 * H * 4;  // NN*2 f32
static constexpr size_t OFF_SCSH = OFF_S + (size_t)NN * 2 * 4;         // 4*H f32
static constexpr size_t OFF_NUMP = OFF_SCSH + 4 * H * 4;               // EB*NB f32
static constexpr size_t OFF_DENP = OFF_NUMP + (size_t)EB * NB * 4;     // EB*NB f32
static constexpr size_t OFF_GST  = OFF_DENP + (size_t)EB * NB * 4;     // 3*NB f32 (ss00,ss01,ss11)

// ---------------- kernels ----------------

// x0 = node_feature @ W_pre + b_pre   (8 nodes per 128-thread block)
__global__ void k_pre(const float* __restrict__ nf, const float* __restrict__ Wp,
                      const float* __restrict__ bp, float* __restrict__ x0) {
    __shared__ float sW[FIN * H];
    __shared__ float sNF[8 * FIN];
    int tid = threadIdx.x;
    for (int i = tid; i < FIN * H; i += 128) sW[i] = Wp[i];
    int n0 = blockIdx.x * 8;
    sNF[tid] = nf[n0 * FIN + tid];
    __syncthreads();
    float b = bp[tid];
    #pragma unroll
    for (int r = 0; r < 8; ++r) {
        float acc = b;
        #pragma unroll
        for (int f = 0; f < FIN; ++f) acc += sNF[r * FIN + f] * sW[f * H + tid];
        x0[(size_t)(n0 + r) * H + tid] = acc;
    }
}

__global__ void k_count(const int* __restrict__ dst, int* __restrict__ cnt) {
    int e = blockIdx.x * 256 + threadIdx.x;
    if (e < NE) atomicAdd(&cnt[dst[e]], 1);
}

// single block of 1024 threads: exclusive scan of 32768 counts
__global__ void k_scan(const int* __restrict__ cnt, int* __restrict__ offs,
                       int* __restrict__ curs) {
    __shared__ int sd[1024];
    int t = threadIdx.x;
    int base = t * 32;
    int s = 0;
    #pragma unroll
    for (int i = 0; i < 32; ++i) s += cnt[base + i];
    sd[t] = s;
    __syncthreads();
    for (int off = 1; off < 1024; off <<= 1) {
        int v = (t >= off) ? sd[t - off] : 0;
        __syncthreads();
        sd[t] += v;
        __syncthreads();
    }
    int run = sd[t] - s;  // exclusive prefix
    for (int i = 0; i < 32; ++i) {
        int c = cnt[base + i];
        offs[base + i] = run;
        curs[base + i] = run;
        run += c;
    }
    if (t == 1023) offs[NN] = run;  // == NE
}

__global__ void k_scatter(const int* __restrict__ src, const int* __restrict__ dst,
                          const float* __restrict__ ew, int* __restrict__ curs,
                          int* __restrict__ ssrc, float* __restrict__ sw) {
    int e = blockIdx.x * 256 + threadIdx.x;
    if (e < NE) {
        int d = dst[e];
        int p = atomicAdd(&curs[d], 1);
        ssrc[p] = src[e];
        sw[p] = ew[e];
    }
}

// agg[node,h] = sum_{e in CSR[node]} w_e * x[src_e, h]    (block = 1 node, 128 threads)
__global__ void k_agg(const float* __restrict__ x, const int* __restrict__ offs,
                      const int* __restrict__ ssrc, const float* __restrict__ sw,
                      float* __restrict__ agg) {
    int bid = blockIdx.x;
    int node = (bid & 7) * (NN / 8) + (bid >> 3);  // XCD-locality swizzle: 8 graphs per XCD
    int h = threadIdx.x;
    int beg = offs[node], end = offs[node + 1];
    float acc = 0.f;
    int j = beg;
    for (; j + 4 <= end; j += 4) {
        int s0 = ssrc[j], s1 = ssrc[j + 1], s2 = ssrc[j + 2], s3 = ssrc[j + 3];
        float w0 = sw[j], w1 = sw[j + 1], w2 = sw[j + 2], w3 = sw[j + 3];
        float v0 = x[(size_t)s0 * H + h], v1 = x[(size_t)s1 * H + h];
        float v2 = x[(size_t)s2 * H + h], v3 = x[(size_t)s3 * H + h];
        acc += w0 * v0;
        acc += w1 * v1;
        acc += w2 * v2;
        acc += w3 * v3;
    }
    for (; j < end; ++j) acc += sw[j] * x[(size_t)ssrc[j] * H + h];
    agg[(size_t)node * H + h] = acc;
}

// Y = Amat@Wrel + Xmat@Wroot + brel ; fused BN column-stat partials (8 shadow copies).
// Block: 64 rows x 128 cols, 256 threads, 8x4 per-thread tile. Y may alias Amat.
__global__ __launch_bounds__(256) void k_gemm(
        const float* Amat, const float* __restrict__ Xmat,
        const float* __restrict__ Wrel, const float* __restrict__ Wroot,
        const float* __restrict__ brel, float* Y,
        float* __restrict__ bn_base) {
    __shared__ float At[32][64];    // A tile transposed [k][row]
    __shared__ float Wt[32][128];   // W tile [k][col]
    __shared__ float colS[128], colQ[128];
    int tid = threadIdx.x;
    int tc = tid & 31;   // col group (4 cols)
    int tr = tid >> 5;   // row group (8 rows)
    int row0 = blockIdx.x * 64;
    float acc[8][4];
    #pragma unroll
    for (int r = 0; r < 8; ++r)
        #pragma unroll
        for (int c = 0; c < 4; ++c) acc[r][c] = 0.f;

    int lr = tid & 63;    // A-load row
    int lkb = tid >> 6;   // A-load k base (0..3)
    int lc = tid & 127;   // W-load col
    int lkb2 = tid >> 7;  // W-load k base (0..1)

    for (int m = 0; m < 2; ++m) {
        const float* A = m ? Xmat : Amat;
        const float* __restrict__ W = m ? Wroot : Wrel;
        for (int k0 = 0; k0 < H; k0 += 32) {
            __syncthreads();
            #pragma unroll
            for (int i = 0; i < 8; ++i) {
                int kk = lkb + 4 * i;
                At[kk][lr] = A[(size_t)(row0 + lr) * H + k0 + kk];
            }
            #pragma unroll
            for (int i = 0; i < 16; ++i) {
                int kk = lkb2 + 2 * i;
                Wt[kk][lc] = W[(size_t)(k0 + kk) * H + lc];
            }
            __syncthreads();
            #pragma unroll
            for (int k = 0; k < 32; ++k) {
                float4 w4 = *(const float4*)&Wt[k][tc * 4];
                float4 a0 = *(const float4*)&At[k][tr * 8];
                float4 a1 = *(const float4*)&At[k][tr * 8 + 4];
                float av[8] = {a0.x, a0.y, a0.z, a0.w, a1.x, a1.y, a1.z, a1.w};
                float wv[4] = {w4.x, w4.y, w4.z, w4.w};
                #pragma unroll
                for (int r = 0; r < 8; ++r)
                    #pragma unroll
                    for (int c = 0; c < 4; ++c) acc[r][c] += av[r] * wv[c];
            }
        }
    }
    // epilogue: bias, store, BN partials
    float bb[4];
    #pragma unroll
    for (int c = 0; c < 4; ++c) bb[c] = brel[tc * 4 + c];
    float ls[4] = {0, 0, 0, 0}, lq[4] = {0, 0, 0, 0};
    #pragma unroll
    for (int r = 0; r < 8; ++r) {
        int row = row0 + tr * 8 + r;
        float v0 = acc[r][0] + bb[0], v1 = acc[r][1] + bb[1];
        float v2 = acc[r][2] + bb[2], v3 = acc[r][3] + bb[3];
        float4 o; o.x = v0; o.y = v1; o.z = v2; o.w = v3;
        *(float4*)&Y[(size_t)row * H + tc * 4] = o;
        ls[0] += v0; lq[0] += v0 * v0;
        ls[1] += v1; lq[1] += v1 * v1;
        ls[2] += v2; lq[2] += v2 * v2;
        ls[3] += v3; lq[3] += v3 * v3;
    }
    __syncthreads();
    if (tid < 128) { colS[tid] = 0.f; colQ[tid] = 0.f; }
    __syncthreads();
    #pragma unroll
    for (int c = 0; c < 4; ++c) {
        atomicAdd(&colS[tc * 4 + c], ls[c]);
        atomicAdd(&colQ[tc * 4 + c], lq[c]);
    }
    __syncthreads();
    if (tid < 128) {
        int sh = blockIdx.x & 7;  // shadow copy -> 64-deep chains instead of 512
        atomicAdd(&bn_base[(sh * 2 + 0) * H + tid], colS[tid]);
        atomicAdd(&bn_base[(sh * 2 + 1) * H + tid], colQ[tid]);
    }
}

// finalize BN from 8 shadow copies: scale = rsqrt(var+eps)*g ; shift = be - mu*scale
__global__ void k_bnfinal(const float* __restrict__ bn_base, const float* __restrict__ g,
                          const float* __restrict__ be, float* __restrict__ sc_sh) {
    int t = threadIdx.x;
    float su = 0.f, sq = 0.f;
    #pragma unroll
    for (int sh = 0; sh < 8; ++sh) {
        su += bn_base[(sh * 2 + 0) * H + t];
        sq += bn_base[(sh * 2 + 1) * H + t];
    }
    float mu = su * (1.f / NN);
    float var = sq * (1.f / NN) - mu * mu;
    float sc = rsqrtf(var + BN_EPS) * g[t];
    sc_sh[t] = sc;
    sc_sh[H + t] = be[t] - mu * sc;
}

// in-place x = relu(y*scale + shift), float4
__global__ void k_bnrelu(float* __restrict__ y, const float* __restrict__ sc_sh) {
    int idx = blockIdx.x * 256 + threadIdx.x;
    int c = (idx & 31) * 4;
    float4 v = ((const float4*)y)[idx];
    float4 sc = *(const float4*)&sc_sh[c];
    float4 sh = *(const float4*)&sc_sh[H + c];
    v.x = fmaxf(fmaf(v.x, sc.x, sh.x), 0.f);
    v.y = fmaxf(fmaf(v.y, sc.y, sh.y), 0.f);
    v.z = fmaxf(fmaf(v.z, sc.z, sh.z), 0.f);
    v.w = fmaxf(fmaf(v.w, sc.w, sh.w), 0.f);
    ((float4*)y)[idx] = v;
}

// s = softmax(x @ W_pool + b_pool): one wave per node
__global__ void k_pool_s(const float* __restrict__ x, const float* __restrict__ Wp,
                         const float* __restrict__ bp, float* __restrict__ s) {
    int tid = threadIdx.x;
    int lane = tid & 63, wv = tid >> 6;
    int n = blockIdx.x * 4 + wv;
    const float* xr = x + (size_t)n * H;
    float x0 = xr[lane], x1 = xr[lane + 64];
    float z0 = x0 * Wp[lane * 2] + x1 * Wp[(lane + 64) * 2];
    float z1 = x0 * Wp[lane * 2 + 1] + x1 * Wp[(lane + 64) * 2 + 1];
    for (int o = 32; o; o >>= 1) { z0 += __shfl_down(z0, o); z1 += __shfl_down(z1, o); }
    if (lane == 0) {
        z0 += bp[0]; z1 += bp[1];
        float m = fmaxf(z0, z1);
        float e0 = expf(z0 - m), e1 = expf(z1 - m);
        float inv = 1.f / (e0 + e1);
        s[n * 2] = e0 * inv;
        s[n * 2 + 1] = e1 * inv;
    }
}

// pool[b,k,h] += sum_n s[n,k]*x[n,h]   (block = 64-node chunk of one graph)
__global__ void k_pool_out(const float* __restrict__ x, const float* __restrict__ s,
                           float* __restrict__ pool) {
    int b = blockIdx.x & 63, chunk = blockIdx.x >> 6;
    int h = threadIdx.x;
    float a0 = 0.f, a1 = 0.f;
    int n0 = b * NP + chunk * 64;
    for (int i = 0; i < 64; ++i) {
        float2 sv = ((const float2*)s)[n0 + i];
        float xv = x[(size_t)(n0 + i) * H + h];
        a0 += sv.x * xv;
        a1 += sv.y * xv;
    }
    atomicAdd(&pool[(b * 2 + 0) * H + h], a0);
    atomicAdd(&pool[(b * 2 + 1) * H + h], a1);
}

// per-edge pass: num[b] += w*<s[src],s[dst]> ; den[b] += w*|s[src]|^2
// grid-stride, LDS accumulation, NON-atomic per-block partial output.
__global__ void k_edge_stats(const int* __restrict__ src, const int* __restrict__ dst,
                             const float* __restrict__ ew, const float* __restrict__ s,
                             float* __restrict__ numP, float* __restrict__ denP) {
    __shared__ float ln[NB], ld[NB];
    int t = threadIdx.x;
    if (t < NB) { ln[t] = 0.f; ld[t] = 0.f; }
    __syncthreads();
    for (int e = blockIdx.x * 256 + t; e < NE; e += EB * 256) {
        int a = src[e], d = dst[e];
        float w = ew[e];
        float2 sa = ((const float2*)s)[a];
        float2 sd = ((const float2*)s)[d];
        int g = a >> 9;
        atomicAdd(&ln[g], w * (sa.x * sd.x + sa.y * sd.y));
        atomicAdd(&ld[g], w * (sa.x * sa.x + sa.y * sa.y));
    }
    __syncthreads();
    if (t < NB) {
        numP[blockIdx.x * NB + t] = ln[t];
        denP[blockIdx.x * NB + t] = ld[t];
    }
}

// per-graph node sums for ss: p00, p01, p11
__global__ void k_graph_stats(const float* __restrict__ s, float* __restrict__ gst) {
    int b = blockIdx.x;
    int t = threadIdx.x;  // 128
    float p00 = 0.f, p01 = 0.f, p11 = 0.f;
    for (int i = t; i < NP; i += 128) {
        int n = b * NP + i;
        float2 sv = ((const float2*)s)[n];
        p00 += sv.x * sv.x;
        p01 += sv.x * sv.y;
        p11 += sv.y * sv.y;
    }
    for (int o = 32; o; o >>= 1) {
        p00 += __shfl_down(p00, o);
        p01 += __shfl_down(p01, o);
        p11 += __shfl_down(p11, o);
    }
    __shared__ float tmp[3][2];
    if ((t & 63) == 0) {
        int w = t >> 6;
        tmp[0][w] = p00; tmp[1][w] = p01; tmp[2][w] = p11;
    }
    __syncthreads();
    if (t == 0) {
        gst[b] = tmp[0][0] + tmp[0][1];
        gst[NB + b] = tmp[1][0] + tmp[1][1];
        gst[2 * NB + b] = tmp[2][0] + tmp[2][1];
    }
}

// logits[b,:] = relu(pool[b]).flatten @ W_post + b_post
__global__ void k_logits(const float* __restrict__ pool, const float* __restrict__ Wpost,
                         const float* __restrict__ bpost, float* __restrict__ out) {
    int b = blockIdx.x, t = threadIdx.x;  // 256
    float v = pool[b * 256 + t];
    v = v > 0.f ? v : 0.f;
    float p0 = v * Wpost[t * 2], p1 = v * Wpost[t * 2 + 1];
    for (int o = 32; o; o >>= 1) { p0 += __shfl_down(p0, o); p1 += __shfl_down(p1, o); }
    __shared__ float t0[4], t1[4];
    if ((t & 63) == 0) { t0[t >> 6] = p0; t1[t >> 6] = p1; }
    __syncthreads();
    if (t == 0) {
        out[b * 2] = t0[0] + t0[1] + t0[2] + t0[3] + bpost[0];
        out[b * 2 + 1] = t1[0] + t1[1] + t1[2] + t1[3] + bpost[1];
    }
}

// reduce edge partials + compute both losses. 256 threads, 1 block.
__global__ void k_losses(const float* __restrict__ numP, const float* __restrict__ denP,
                         const float* __restrict__ gst, float* __restrict__ out) {
    __shared__ float rn[4][NB], rd[4][NB];
    int t = threadIdx.x;
    int g = t & 63, q = t >> 6;
    float sn = 0.f, sd = 0.f;
    for (int i = q * (EB / 4); i < (q + 1) * (EB / 4); ++i) {
        sn += numP[i * NB + g];
        sd += denP[i * NB + g];
    }
    rn[q][g] = sn; rd[q][g] = sd;
    __syncthreads();
    if (t < NB) {
        float num = rn[0][t] + rn[1][t] + rn[2][t] + rn[3][t];
        float den = rd[0][t] + rd[1][t] + rd[2][t] + rd[3][t];
        float s00 = gst[t], s01 = gst[NB + t], s11 = gst[2 * NB + t];
        float mc = -(num / den);
        float nrm = sqrtf(s00 * s00 + 2.f * s01 * s01 + s11 * s11);
        const float a = 0.70710678118654752440f;  // 1/sqrt(2)
        float d00 = s00 / nrm - a, d01 = s01 / nrm, d11 = s11 / nrm - a;
        float ol = sqrtf(d00 * d00 + 2.f * d01 * d01 + d11 * d11);
        for (int o = 32; o; o >>= 1) { mc += __shfl_down(mc, o); ol += __shfl_down(ol, o); }
        if (t == 0) {
            out[NB * 2] = mc * (1.f / NB);
            out[NB * 2 + 1] = ol * (1.f / NB);
        }
    }
}

// ---------------- launch ----------------
extern "C" void kernel_launch(void* const* d_in, const int* in_sizes, int n_in,
                              void* d_out, int out_size, void* d_ws, size_t ws_size,
                              hipStream_t stream) {
    const float* nf     = (const float*)d_in[0];
    const int*   ei     = (const int*)d_in[1];
    const float* ew     = (const float*)d_in[2];
    const float* W_pre  = (const float*)d_in[4];
    const float* b_pre  = (const float*)d_in[5];
    const float* W1_rel = (const float*)d_in[6];
    const float* b1_rel = (const float*)d_in[7];
    const float* W1_root= (const float*)d_in[8];
    const float* g1     = (const float*)d_in[9];
    const float* be1    = (const float*)d_in[10];
    const float* W2_rel = (const float*)d_in[11];
    const float* b2_rel = (const float*)d_in[12];
    const float* W2_root= (const float*)d_in[13];
    const float* g2     = (const float*)d_in[14];
    const float* be2    = (const float*)d_in[15];
    const float* W_pool = (const float*)d_in[16];
    const float* b_pool = (const float*)d_in[17];
    const float* W_post = (const float*)d_in[18];
    const float* b_post = (const float*)d_in[19];

    char* ws = (char*)d_ws;
    float* bufA  = (float*)(ws + OFF_BUFA);
    float* bufB  = (float*)(ws + OFF_BUFB);
    int*   ssrc  = (int*)(ws + OFF_SSRC);
    float* sw    = (float*)(ws + OFF_SW);
    int*   offs  = (int*)(ws + OFF_OFFS);
    int*   curs  = (int*)(ws + OFF_CURS);
    int*   cnt   = (int*)(ws + OFF_CNT);
    float* bn    = (float*)(ws + OFF_BN);
    float* pool  = (float*)(ws + OFF_POOL);
    float* sarr  = (float*)(ws + OFF_S);
    float* scsh  = (float*)(ws + OFF_SCSH);
    float* numP  = (float*)(ws + OFF_NUMP);
    float* denP  = (float*)(ws + OFF_DENP);
    float* gst   = (float*)(ws + OFF_GST);
    float* outF  = (float*)d_out;

    const int* srcA = ei;
    const int* dstA = ei + NE;
    float* bn1 = bn;
    float* bn2 = (float*)(ws + OFF_BN + SZ_BNL);

    hipMemsetAsync(ws + OFF_ZERO, 0, ZERO_BYTES, stream);

    k_pre<<<NN / 8, 128, 0, stream>>>(nf, W_pre, b_pre, bufA);
    k_count<<<NE / 256, 256, 0, stream>>>(dstA, cnt);
    k_scan<<<1, 1024, 0, stream>>>(cnt, offs, curs);
    k_scatter<<<NE / 256, 256, 0, stream>>>(srcA, dstA, ew, curs, ssrc, sw);

    // layer 1
    k_agg<<<NN, 128, 0, stream>>>(bufA, offs, ssrc, sw, bufB);
    k_gemm<<<NN / 64, 256, 0, stream>>>(bufB, bufA, W1_rel, W1_root, b1_rel, bufB, bn1);
    k_bnfinal<<<1, H, 0, stream>>>(bn1, g1, be1, scsh);
    k_bnrelu<<<(NN * H / 4) / 256, 256, 0, stream>>>(bufB, scsh);

    // layer 2
    k_agg<<<NN, 128, 0, stream>>>(bufB, offs, ssrc, sw, bufA);
    k_gemm<<<NN / 64, 256, 0, stream>>>(bufA, bufB, W2_rel, W2_root, b2_rel, bufA, bn2);
    k_bnfinal<<<1, H, 0, stream>>>(bn2, g2, be2, scsh + 2 * H);
    k_bnrelu<<<(NN * H / 4) / 256, 256, 0, stream>>>(bufA, scsh + 2 * H);

    // pooling + losses
    k_pool_s<<<NN / 4, 256, 0, stream>>>(bufA, W_pool, b_pool, sarr);
    k_pool_out<<<8 * NB, 128, 0, stream>>>(bufA, sarr, pool);
    k_edge_stats<<<EB, 256, 0, stream>>>(srcA, dstA, ew, sarr, numP, denP);
    k_graph_stats<<<NB, 128, 0, stream>>>(sarr, gst);
    k_logits<<<NB, 256, 0, stream>>>(pool, W_post, b_post, outF);
    k_losses<<<1, 256, 0, stream>>>(numP, denP, gst, outF);
}

// Round 3
// 407.808 us; speedup vs baseline: 1.5711x; 1.1784x over previous
//
#include <hip/hip_runtime.h>

#define NN 32768      // total nodes
#define NP 512        // nodes per graph
#define NB 64         // graphs
#define NE 1048576    // edges
#define FIN 16
#define H 128
#define BN_EPS 1e-5f
#define EPB 4096      // edges per hist/scatterA block
#define NBLK (NE / EPB)   // 256
#define CAPH 8704     // max edges per half-graph (mean 8192, +5.7 sigma)

// ---------------- workspace layout (bytes) ----------------
static constexpr size_t SZ_BUF    = (size_t)NN * H * 4;            // 16 MiB
static constexpr size_t OFF_BUFA  = 0;
static constexpr size_t OFF_BUFB  = OFF_BUFA + SZ_BUF;
static constexpr size_t OFF_TMP   = OFF_BUFB;                      // alias: graph-sorted tmp (8 MiB), dead before bufB written
static constexpr size_t OFF_SORT  = OFF_BUFB + SZ_BUF;             // NE int2 (8 MiB)
static constexpr size_t OFF_OFFS  = OFF_SORT + (size_t)NE * 8;     // NN+8 ints
static constexpr size_t OFF_HISTG = OFF_OFFS + ((size_t)NN + 128) * 4;   // NBLK*NB ints
static constexpr size_t OFF_STARTG= OFF_HISTG + (size_t)NBLK * NB * 4;
static constexpr size_t OFF_GBASE = OFF_STARTG + (size_t)NBLK * NB * 4;  // 65 ints
static constexpr size_t OFF_S     = OFF_GBASE + 512;               // NN*2 f32
static constexpr size_t OFF_SCSH  = OFF_S + (size_t)NN * 2 * 4;    // 4*H f32
static constexpr size_t OFF_GST   = OFF_SCSH + 4 * H * 4;          // 3*NB f32
// --- zeroed region (one memset) ---
static constexpr size_t OFF_ZERO  = OFF_GST + 1024;
static constexpr size_t OFF_NUM   = OFF_ZERO;                      // NB f32
static constexpr size_t OFF_DEN   = OFF_NUM + 256;                 // NB f32
static constexpr size_t OFF_BN    = OFF_DEN + 256;                 // 2 layers * 8 shadows * 2 * H f32
static constexpr size_t SZ_BNL    = (size_t)8 * 2 * H * 4;
static constexpr size_t OFF_POOL  = OFF_BN + 2 * SZ_BNL;           // NB*2*H f32
static constexpr size_t ZERO_BYTES= (OFF_POOL + (size_t)NB * 2 * H * 4) - OFF_ZERO;

// ---------------- kernels ----------------

// x0 = node_feature @ W_pre + b_pre   (8 nodes per 128-thread block)
__global__ void k_pre(const float* __restrict__ nf, const float* __restrict__ Wp,
                      const float* __restrict__ bp, float* __restrict__ x0) {
    __shared__ float sW[FIN * H];
    __shared__ float sNF[8 * FIN];
    int tid = threadIdx.x;
    for (int i = tid; i < FIN * H; i += 128) sW[i] = Wp[i];
    int n0 = blockIdx.x * 8;
    sNF[tid] = nf[n0 * FIN + tid];
    __syncthreads();
    float b = bp[tid];
    #pragma unroll
    for (int r = 0; r < 8; ++r) {
        float acc = b;
        #pragma unroll
        for (int f = 0; f < FIN; ++f) acc += sNF[r * FIN + f] * sW[f * H + tid];
        x0[(size_t)(n0 + r) * H + tid] = acc;
    }
}

// per-block histogram of edges by graph
__global__ __launch_bounds__(256) void k_hist(const int* __restrict__ src,
                                              int* __restrict__ histG) {
    __shared__ int h[NB];
    int t = threadIdx.x, bid = blockIdx.x;
    if (t < NB) h[t] = 0;
    __syncthreads();
    int ebase = bid * EPB;
    #pragma unroll
    for (int i = 0; i < EPB / 256; ++i) {
        int s = src[ebase + i * 256 + t];
        atomicAdd(&h[s >> 9], 1);
    }
    __syncthreads();
    if (t < NB) histG[bid * NB + t] = h[t];
}

// scan histG -> per-(block,graph) global bases + per-graph bases. 1 block, 64 threads.
__global__ void k_scanG(const int* __restrict__ histG, int* __restrict__ startG,
                        int* __restrict__ gbase) {
    int g = threadIdx.x;  // 64 = 1 wave
    int run = 0;
    for (int b = 0; b < NBLK; ++b) {
        int v = histG[b * NB + g];
        startG[b * NB + g] = run;   // within-graph prefix (temp)
        run += v;
    }
    int x = run;
    #pragma unroll
    for (int o = 1; o < 64; o <<= 1) {
        int y = __shfl_up(x, o);
        if (g >= o) x += y;
    }
    int base = x - run;  // exclusive prefix over graphs
    gbase[g] = base;
    if (g == 63) gbase[64] = x;  // == NE
    for (int b = 0; b < NBLK; ++b) startG[b * NB + g] += base;
}

// LDS-staged graph-sort of each 4096-edge chunk -> coalesced writes into
// graph-contiguous tmp. Record: {src_local | dst_local<<9, w_bits}.
__global__ __launch_bounds__(256) void k_scatterA(
        const int* __restrict__ src, const int* __restrict__ dst,
        const float* __restrict__ ew, const int* __restrict__ histG,
        const int* __restrict__ startG, int2* __restrict__ tmp) {
    __shared__ int lstart[NB + 1];
    __shared__ int cursor[NB];
    __shared__ int gdst[NB];
    __shared__ int2 buf[EPB];   // 32 KB
    int t = threadIdx.x, bid = blockIdx.x;
    if (t < NB) {
        int c = histG[bid * NB + t];
        int x = c;
        #pragma unroll
        for (int o = 1; o < 64; o <<= 1) {
            int y = __shfl_up(x, o);
            if (t >= o) x += y;
        }
        lstart[t] = x - c;
        cursor[t] = x - c;
        gdst[t] = startG[bid * NB + t];
        if (t == 63) lstart[NB] = x;  // == EPB
    }
    __syncthreads();
    int ebase = bid * EPB;
    #pragma unroll
    for (int i = 0; i < EPB / 256; ++i) {
        int e = ebase + i * 256 + t;
        int s = src[e], d = dst[e];
        float w = ew[e];
        int g = s >> 9;
        int meta = (s & 511) | ((d & 511) << 9);
        int p = atomicAdd(&cursor[g], 1);
        buf[p] = make_int2(meta, __float_as_int(w));
    }
    __syncthreads();
    // stream out per graph chunk (coalesced)
    for (int g = 0; g < NB; ++g) {
        int lo = lstart[g], hi = lstart[g + 1];
        int base = gdst[g];
        for (int i = lo + t; i < hi; i += 256) tmp[base + (i - lo)] = buf[i];
    }
}

// per-graph counting sort by dst (2 blocks/graph, each owns 256 dst nodes).
// Emits final CSR (sequential writes) + per-node offs.
__global__ __launch_bounds__(512) void k_sortB(
        const int2* __restrict__ tmp, const int* __restrict__ gbase,
        int2* __restrict__ sorted, int* __restrict__ offs) {
    __shared__ int hist[NP];
    __shared__ int start[NP + 1];
    __shared__ int cursor[NP / 2];
    __shared__ int perm[CAPH];   // 34 KB
    int t = threadIdx.x;
    int g = blockIdx.x >> 1, half = blockIdx.x & 1;
    int gbeg = gbase[g], gend = gbase[g + 1];
    int cnt = gend - gbeg;
    if (t < NP) hist[t] = 0;
    __syncthreads();
    for (int i = t; i < cnt; i += 512) {
        int meta = tmp[gbeg + i].x;
        atomicAdd(&hist[(meta >> 9) & 511], 1);
    }
    __syncthreads();
    if (t < NP) start[t] = hist[t];
    __syncthreads();
    for (int o = 1; o < NP; o <<= 1) {   // Hillis-Steele inclusive scan
        int v = 0;
        if (t >= o && t < NP) v = start[t - o];
        __syncthreads();
        if (t < NP) start[t] += v;
        __syncthreads();
    }
    if (t < NP) start[t] -= hist[t];     // exclusive
    if (t == 0) start[NP] = cnt;
    __syncthreads();
    int h0 = half * 256;
    if (t < 256) {
        int n = h0 + t;
        offs[g * NP + n] = gbeg + start[n];
        cursor[t] = start[n];
    }
    if (blockIdx.x == 0 && t == 0) offs[NN] = NE;
    __syncthreads();
    int ha = start[h0];
    int hb = half ? cnt : start[256];
    for (int i = t; i < cnt; i += 512) {     // place my half's edges
        int meta = tmp[gbeg + i].x;
        int d = (meta >> 9) & 511;
        if ((d >> 8) == half) {
            int p = atomicAdd(&cursor[d - h0], 1);
            perm[p - ha] = i;
        }
    }
    __syncthreads();
    for (int o = ha + t; o < hb; o += 512) {  // gather + sequential write
        sorted[gbeg + o] = tmp[gbeg + perm[o - ha]];
    }
}

// agg[node,h] = sum_{e in CSR[node]} w_e * x[src_e, h]    (block = 1 node, 128 threads)
__global__ void k_agg(const float* __restrict__ x, const int* __restrict__ offs,
                      const int2* __restrict__ rec, float* __restrict__ agg) {
    int bid = blockIdx.x;
    int node = (bid & 7) * (NN / 8) + (bid >> 3);  // XCD-locality swizzle
    int h = threadIdx.x;
    int sbase = node & ~(NP - 1);   // graph's first node
    int beg = offs[node], end = offs[node + 1];
    float acc = 0.f;
    int j = beg;
    for (; j + 4 <= end; j += 4) {
        int2 r0 = rec[j], r1 = rec[j + 1], r2 = rec[j + 2], r3 = rec[j + 3];
        float v0 = x[(size_t)(sbase + (r0.x & 511)) * H + h];
        float v1 = x[(size_t)(sbase + (r1.x & 511)) * H + h];
        float v2 = x[(size_t)(sbase + (r2.x & 511)) * H + h];
        float v3 = x[(size_t)(sbase + (r3.x & 511)) * H + h];
        acc += __int_as_float(r0.y) * v0;
        acc += __int_as_float(r1.y) * v1;
        acc += __int_as_float(r2.y) * v2;
        acc += __int_as_float(r3.y) * v3;
    }
    for (; j < end; ++j)
        acc += __int_as_float(rec[j].y) * x[(size_t)(sbase + (rec[j].x & 511)) * H + h];
    agg[(size_t)node * H + h] = acc;
}

// Y = Amat@Wrel + Xmat@Wroot + brel ; fused BN column-stat partials (8 shadow copies).
__global__ __launch_bounds__(256) void k_gemm(
        const float* Amat, const float* __restrict__ Xmat,
        const float* __restrict__ Wrel, const float* __restrict__ Wroot,
        const float* __restrict__ brel, float* Y,
        float* __restrict__ bn_base) {
    __shared__ float At[32][64];
    __shared__ float Wt[32][128];
    __shared__ float colS[128], colQ[128];
    int tid = threadIdx.x;
    int tc = tid & 31;
    int tr = tid >> 5;
    int row0 = blockIdx.x * 64;
    float acc[8][4];
    #pragma unroll
    for (int r = 0; r < 8; ++r)
        #pragma unroll
        for (int c = 0; c < 4; ++c) acc[r][c] = 0.f;

    int lr = tid & 63;
    int lkb = tid >> 6;
    int lc = tid & 127;
    int lkb2 = tid >> 7;

    for (int m = 0; m < 2; ++m) {
        const float* A = m ? Xmat : Amat;
        const float* __restrict__ W = m ? Wroot : Wrel;
        for (int k0 = 0; k0 < H; k0 += 32) {
            __syncthreads();
            #pragma unroll
            for (int i = 0; i < 8; ++i) {
                int kk = lkb + 4 * i;
                At[kk][lr] = A[(size_t)(row0 + lr) * H + k0 + kk];
            }
            #pragma unroll
            for (int i = 0; i < 16; ++i) {
                int kk = lkb2 + 2 * i;
                Wt[kk][lc] = W[(size_t)(k0 + kk) * H + lc];
            }
            __syncthreads();
            #pragma unroll
            for (int k = 0; k < 32; ++k) {
                float4 w4 = *(const float4*)&Wt[k][tc * 4];
                float4 a0 = *(const float4*)&At[k][tr * 8];
                float4 a1 = *(const float4*)&At[k][tr * 8 + 4];
                float av[8] = {a0.x, a0.y, a0.z, a0.w, a1.x, a1.y, a1.z, a1.w};
                float wv[4] = {w4.x, w4.y, w4.z, w4.w};
                #pragma unroll
                for (int r = 0; r < 8; ++r)
                    #pragma unroll
                    for (int c = 0; c < 4; ++c) acc[r][c] += av[r] * wv[c];
            }
        }
    }
    float bb[4];
    #pragma unroll
    for (int c = 0; c < 4; ++c) bb[c] = brel[tc * 4 + c];
    float ls[4] = {0, 0, 0, 0}, lq[4] = {0, 0, 0, 0};
    #pragma unroll
    for (int r = 0; r < 8; ++r) {
        int row = row0 + tr * 8 + r;
        float v0 = acc[r][0] + bb[0], v1 = acc[r][1] + bb[1];
        float v2 = acc[r][2] + bb[2], v3 = acc[r][3] + bb[3];
        float4 o; o.x = v0; o.y = v1; o.z = v2; o.w = v3;
        *(float4*)&Y[(size_t)row * H + tc * 4] = o;
        ls[0] += v0; lq[0] += v0 * v0;
        ls[1] += v1; lq[1] += v1 * v1;
        ls[2] += v2; lq[2] += v2 * v2;
        ls[3] += v3; lq[3] += v3 * v3;
    }
    __syncthreads();
    if (tid < 128) { colS[tid] = 0.f; colQ[tid] = 0.f; }
    __syncthreads();
    #pragma unroll
    for (int c = 0; c < 4; ++c) {
        atomicAdd(&colS[tc * 4 + c], ls[c]);
        atomicAdd(&colQ[tc * 4 + c], lq[c]);
    }
    __syncthreads();
    if (tid < 128) {
        int sh = blockIdx.x & 7;
        atomicAdd(&bn_base[(sh * 2 + 0) * H + tid], colS[tid]);
        atomicAdd(&bn_base[(sh * 2 + 1) * H + tid], colQ[tid]);
    }
}

__global__ void k_bnfinal(const float* __restrict__ bn_base, const float* __restrict__ g,
                          const float* __restrict__ be, float* __restrict__ sc_sh) {
    int t = threadIdx.x;
    float su = 0.f, sq = 0.f;
    #pragma unroll
    for (int sh = 0; sh < 8; ++sh) {
        su += bn_base[(sh * 2 + 0) * H + t];
        sq += bn_base[(sh * 2 + 1) * H + t];
    }
    float mu = su * (1.f / NN);
    float var = sq * (1.f / NN) - mu * mu;
    float sc = rsqrtf(var + BN_EPS) * g[t];
    sc_sh[t] = sc;
    sc_sh[H + t] = be[t] - mu * sc;
}

__global__ void k_bnrelu(float* __restrict__ y, const float* __restrict__ sc_sh) {
    int idx = blockIdx.x * 256 + threadIdx.x;
    int c = (idx & 31) * 4;
    float4 v = ((const float4*)y)[idx];
    float4 sc = *(const float4*)&sc_sh[c];
    float4 sh = *(const float4*)&sc_sh[H + c];
    v.x = fmaxf(fmaf(v.x, sc.x, sh.x), 0.f);
    v.y = fmaxf(fmaf(v.y, sc.y, sh.y), 0.f);
    v.z = fmaxf(fmaf(v.z, sc.z, sh.z), 0.f);
    v.w = fmaxf(fmaf(v.w, sc.w, sh.w), 0.f);
    ((float4*)y)[idx] = v;
}

// s = softmax(x @ W_pool + b_pool): one wave per node
__global__ void k_pool_s(const float* __restrict__ x, const float* __restrict__ Wp,
                         const float* __restrict__ bp, float* __restrict__ s) {
    int tid = threadIdx.x;
    int lane = tid & 63, wv = tid >> 6;
    int n = blockIdx.x * 4 + wv;
    const float* xr = x + (size_t)n * H;
    float x0 = xr[lane], x1 = xr[lane + 64];
    float z0 = x0 * Wp[lane * 2] + x1 * Wp[(lane + 64) * 2];
    float z1 = x0 * Wp[lane * 2 + 1] + x1 * Wp[(lane + 64) * 2 + 1];
    for (int o = 32; o; o >>= 1) { z0 += __shfl_down(z0, o); z1 += __shfl_down(z1, o); }
    if (lane == 0) {
        z0 += bp[0]; z1 += bp[1];
        float m = fmaxf(z0, z1);
        float e0 = expf(z0 - m), e1 = expf(z1 - m);
        float inv = 1.f / (e0 + e1);
        s[n * 2] = e0 * inv;
        s[n * 2 + 1] = e1 * inv;
    }
}

// pool[b,k,h] += sum_n s[n,k]*x[n,h]   (block = 64-node chunk of one graph)
__global__ void k_pool_out(const float* __restrict__ x, const float* __restrict__ s,
                           float* __restrict__ pool) {
    int b = blockIdx.x & 63, chunk = blockIdx.x >> 6;
    int h = threadIdx.x;
    float a0 = 0.f, a1 = 0.f;
    int n0 = b * NP + chunk * 64;
    for (int i = 0; i < 64; ++i) {
        float2 sv = ((const float2*)s)[n0 + i];
        float xv = x[(size_t)(n0 + i) * H + h];
        a0 += sv.x * xv;
        a1 += sv.y * xv;
    }
    atomicAdd(&pool[(b * 2 + 0) * H + h], a0);
    atomicAdd(&pool[(b * 2 + 1) * H + h], a1);
}

// per-edge stats from sorted records; graph's s rows staged in LDS.
__global__ __launch_bounds__(256) void k_edge_stats(
        const int2* __restrict__ sorted, const int* __restrict__ gbase,
        const float* __restrict__ s, float* __restrict__ num, float* __restrict__ den) {
    __shared__ float2 sl[NP];
    __shared__ float ln[4], ld2[4];
    int t = threadIdx.x;
    int g = blockIdx.x >> 2, q = blockIdx.x & 3;
    int gbeg = gbase[g], gend = gbase[g + 1];
    for (int i = t; i < NP; i += 256) sl[i] = ((const float2*)s)[g * NP + i];
    __syncthreads();
    float an = 0.f, ad = 0.f;
    int cnt = gend - gbeg;
    int q0 = gbeg + (cnt * q) / 4, q1 = gbeg + (cnt * (q + 1)) / 4;
    for (int i = q0 + t; i < q1; i += 256) {
        int2 r = sorted[i];
        float w = __int_as_float(r.y);
        float2 ss = sl[r.x & 511];
        float2 sd = sl[(r.x >> 9) & 511];
        an += w * (ss.x * sd.x + ss.y * sd.y);
        ad += w * (ss.x * ss.x + ss.y * ss.y);
    }
    for (int o = 32; o; o >>= 1) { an += __shfl_down(an, o); ad += __shfl_down(ad, o); }
    if ((t & 63) == 0) { ln[t >> 6] = an; ld2[t >> 6] = ad; }
    __syncthreads();
    if (t == 0) {
        atomicAdd(&num[g], ln[0] + ln[1] + ln[2] + ln[3]);
        atomicAdd(&den[g], ld2[0] + ld2[1] + ld2[2] + ld2[3]);
    }
}

// per-graph node sums for ss: p00, p01, p11
__global__ void k_graph_stats(const float* __restrict__ s, float* __restrict__ gst) {
    int b = blockIdx.x;
    int t = threadIdx.x;  // 128
    float p00 = 0.f, p01 = 0.f, p11 = 0.f;
    for (int i = t; i < NP; i += 128) {
        int n = b * NP + i;
        float2 sv = ((const float2*)s)[n];
        p00 += sv.x * sv.x;
        p01 += sv.x * sv.y;
        p11 += sv.y * sv.y;
    }
    for (int o = 32; o; o >>= 1) {
        p00 += __shfl_down(p00, o);
        p01 += __shfl_down(p01, o);
        p11 += __shfl_down(p11, o);
    }
    __shared__ float tmp[3][2];
    if ((t & 63) == 0) {
        int w = t >> 6;
        tmp[0][w] = p00; tmp[1][w] = p01; tmp[2][w] = p11;
    }
    __syncthreads();
    if (t == 0) {
        gst[b] = tmp[0][0] + tmp[0][1];
        gst[NB + b] = tmp[1][0] + tmp[1][1];
        gst[2 * NB + b] = tmp[2][0] + tmp[2][1];
    }
}

// logits[b,:] = relu(pool[b]).flatten @ W_post + b_post
__global__ void k_logits(const float* __restrict__ pool, const float* __restrict__ Wpost,
                         const float* __restrict__ bpost, float* __restrict__ out) {
    int b = blockIdx.x, t = threadIdx.x;  // 256
    float v = pool[b * 256 + t];
    v = v > 0.f ? v : 0.f;
    float p0 = v * Wpost[t * 2], p1 = v * Wpost[t * 2 + 1];
    for (int o = 32; o; o >>= 1) { p0 += __shfl_down(p0, o); p1 += __shfl_down(p1, o); }
    __shared__ float t0[4], t1[4];
    if ((t & 63) == 0) { t0[t >> 6] = p0; t1[t >> 6] = p1; }
    __syncthreads();
    if (t == 0) {
        out[b * 2] = t0[0] + t0[1] + t0[2] + t0[3] + bpost[0];
        out[b * 2 + 1] = t1[0] + t1[1] + t1[2] + t1[3] + bpost[1];
    }
}

__global__ void k_losses(const float* __restrict__ num, const float* __restrict__ den,
                         const float* __restrict__ gst, float* __restrict__ out) {
    int t = threadIdx.x;  // 64 = 1 wave
    float s00 = gst[t], s01 = gst[NB + t], s11 = gst[2 * NB + t];
    float mc = -(num[t] / den[t]);
    float nrm = sqrtf(s00 * s00 + 2.f * s01 * s01 + s11 * s11);
    const float a = 0.70710678118654752440f;  // 1/sqrt(2)
    float d00 = s00 / nrm - a, d01 = s01 / nrm, d11 = s11 / nrm - a;
    float ol = sqrtf(d00 * d00 + 2.f * d01 * d01 + d11 * d11);
    for (int o = 32; o; o >>= 1) { mc += __shfl_down(mc, o); ol += __shfl_down(ol, o); }
    if (t == 0) {
        out[NB * 2] = mc * (1.f / NB);
        out[NB * 2 + 1] = ol * (1.f / NB);
    }
}

// ---------------- launch ----------------
extern "C" void kernel_launch(void* const* d_in, const int* in_sizes, int n_in,
                              void* d_out, int out_size, void* d_ws, size_t ws_size,
                              hipStream_t stream) {
    const float* nf     = (const float*)d_in[0];
    const int*   ei     = (const int*)d_in[1];
    const float* ew     = (const float*)d_in[2];
    const float* W_pre  = (const float*)d_in[4];
    const float* b_pre  = (const float*)d_in[5];
    const float* W1_rel = (const float*)d_in[6];
    const float* b1_rel = (const float*)d_in[7];
    const float* W1_root= (const float*)d_in[8];
    const float* g1     = (const float*)d_in[9];
    const float* be1    = (const float*)d_in[10];
    const float* W2_rel = (const float*)d_in[11];
    const float* b2_rel = (const float*)d_in[12];
    const float* W2_root= (const float*)d_in[13];
    const float* g2     = (const float*)d_in[14];
    const float* be2    = (const float*)d_in[15];
    const float* W_pool = (const float*)d_in[16];
    const float* b_pool = (const float*)d_in[17];
    const float* W_post = (const float*)d_in[18];
    const float* b_post = (const float*)d_in[19];

    char* ws = (char*)d_ws;
    float* bufA   = (float*)(ws + OFF_BUFA);
    float* bufB   = (float*)(ws + OFF_BUFB);
    int2*  tmp    = (int2*)(ws + OFF_TMP);
    int2*  sorted = (int2*)(ws + OFF_SORT);
    int*   offs   = (int*)(ws + OFF_OFFS);
    int*   histG  = (int*)(ws + OFF_HISTG);
    int*   startG = (int*)(ws + OFF_STARTG);
    int*   gbase  = (int*)(ws + OFF_GBASE);
    float* sarr   = (float*)(ws + OFF_S);
    float* scsh   = (float*)(ws + OFF_SCSH);
    float* gst    = (float*)(ws + OFF_GST);
    float* numA   = (float*)(ws + OFF_NUM);
    float* denA   = (float*)(ws + OFF_DEN);
    float* bn     = (float*)(ws + OFF_BN);
    float* pool   = (float*)(ws + OFF_POOL);
    float* outF   = (float*)d_out;

    const int* srcA = ei;
    const int* dstA = ei + NE;
    float* bn1 = bn;
    float* bn2 = (float*)(ws + OFF_BN + SZ_BNL);

    hipMemsetAsync(ws + OFF_ZERO, 0, ZERO_BYTES, stream);

    // edge sort pipeline (coalesced-writes only)
    k_pre<<<NN / 8, 128, 0, stream>>>(nf, W_pre, b_pre, bufA);
    k_hist<<<NBLK, 256, 0, stream>>>(srcA, histG);
    k_scanG<<<1, 64, 0, stream>>>(histG, startG, gbase);
    k_scatterA<<<NBLK, 256, 0, stream>>>(srcA, dstA, ew, histG, startG, tmp);
    k_sortB<<<2 * NB, 512, 0, stream>>>(tmp, gbase, sorted, offs);

    // layer 1
    k_agg<<<NN, 128, 0, stream>>>(bufA, offs, sorted, bufB);
    k_gemm<<<NN / 64, 256, 0, stream>>>(bufB, bufA, W1_rel, W1_root, b1_rel, bufB, bn1);
    k_bnfinal<<<1, H, 0, stream>>>(bn1, g1, be1, scsh);
    k_bnrelu<<<(NN * H / 4) / 256, 256, 0, stream>>>(bufB, scsh);

    // layer 2
    k_agg<<<NN, 128, 0, stream>>>(bufB, offs, sorted, bufA);
    k_gemm<<<NN / 64, 256, 0, stream>>>(bufA, bufB, W2_rel, W2_root, b2_rel, bufA, bn2);
    k_bnfinal<<<1, H, 0, stream>>>(bn2, g2, be2, scsh + 2 * H);
    k_bnrelu<<<(NN * H / 4) / 256, 256, 0, stream>>>(bufA, scsh + 2 * H);

    // pooling + losses
    k_pool_s<<<NN / 4, 256, 0, stream>>>(bufA, W_pool, b_pool, sarr);
    k_pool_out<<<8 * NB, 128, 0, stream>>>(bufA, sarr, pool);
    k_edge_stats<<<4 * NB, 256, 0, stream>>>(sorted, gbase, sarr, numA, denA);
    k_graph_stats<<<NB, 128, 0, stream>>>(sarr, gst);
    k_logits<<<NB, 256, 0, stream>>>(pool, W_post, b_post, outF);
    k_losses<<<1, 64, 0, stream>>>(numA, denA, gst, outF);
}

// Round 4
// 355.351 us; speedup vs baseline: 1.8030x; 1.1476x over previous
//
#include <hip/hip_runtime.h>

#define NN 32768      // total nodes
#define NP 512        // nodes per graph
#define NB 64         // graphs
#define NE 1048576    // edges
#define FIN 16
#define H 128
#define BN_EPS 1e-5f
#define EPB 4096      // edges per hist/scatterA block
#define NBLK (NE / EPB)   // 256
#define CAPH 8704     // max edges per half-graph
#define NSH 16        // BN shadow copies

// ---------------- workspace layout (bytes) ----------------
static constexpr size_t SZ_BUF    = (size_t)NN * H * 4;            // 16 MiB
static constexpr size_t OFF_BUFA  = 0;
static constexpr size_t OFF_BUFB  = OFF_BUFA + SZ_BUF;
static constexpr size_t OFF_TMP   = OFF_BUFB;                      // alias: graph-sorted tmp (8 MiB)
static constexpr size_t OFF_SORT  = OFF_BUFB + SZ_BUF;             // NE int2 (8 MiB)
static constexpr size_t OFF_OFFS  = OFF_SORT + (size_t)NE * 8;     // NN+8 ints
static constexpr size_t OFF_HISTG = OFF_OFFS + ((size_t)NN + 128) * 4;   // NBLK*NB ints
static constexpr size_t OFF_STARTG= OFF_HISTG + (size_t)NBLK * NB * 4;
static constexpr size_t OFF_GBASE = OFF_STARTG + (size_t)NBLK * NB * 4;  // 65 ints
static constexpr size_t OFF_S     = OFF_GBASE + 512;               // NN*2 f32
static constexpr size_t OFF_SCSH  = OFF_S + (size_t)NN * 2 * 4;    // 4*H f32
static constexpr size_t OFF_GST   = OFF_SCSH + 4 * H * 4;          // 3*NB f32
// --- zeroed region (one memset) ---
static constexpr size_t OFF_ZERO  = OFF_GST + 1024;
static constexpr size_t OFF_NUM   = OFF_ZERO;                      // NB f32
static constexpr size_t OFF_DEN   = OFF_NUM + 256;                 // NB f32
static constexpr size_t OFF_BN    = OFF_DEN + 256;                 // 2 layers * NSH shadows * 2 * H f32
static constexpr size_t SZ_BNL    = (size_t)NSH * 2 * H * 4;
static constexpr size_t OFF_POOL  = OFF_BN + 2 * SZ_BNL;           // NB*2*H f32
static constexpr size_t ZERO_BYTES= (OFF_POOL + (size_t)NB * 2 * H * 4) - OFF_ZERO;

// ---------------- kernels ----------------

// x0 = node_feature @ W_pre + b_pre   (8 nodes per 128-thread block)
__global__ void k_pre(const float* __restrict__ nf, const float* __restrict__ Wp,
                      const float* __restrict__ bp, float* __restrict__ x0) {
    __shared__ float sW[FIN * H];
    __shared__ float sNF[8 * FIN];
    int tid = threadIdx.x;
    for (int i = tid; i < FIN * H; i += 128) sW[i] = Wp[i];
    int n0 = blockIdx.x * 8;
    sNF[tid] = nf[n0 * FIN + tid];
    __syncthreads();
    float b = bp[tid];
    #pragma unroll
    for (int r = 0; r < 8; ++r) {
        float acc = b;
        #pragma unroll
        for (int f = 0; f < FIN; ++f) acc += sNF[r * FIN + f] * sW[f * H + tid];
        x0[(size_t)(n0 + r) * H + tid] = acc;
    }
}

// per-block histogram of edges by graph
__global__ __launch_bounds__(256) void k_hist(const int* __restrict__ src,
                                              int* __restrict__ histG) {
    __shared__ int h[NB];
    int t = threadIdx.x, bid = blockIdx.x;
    if (t < NB) h[t] = 0;
    __syncthreads();
    int ebase = bid * EPB;
    #pragma unroll
    for (int i = 0; i < EPB / 256; ++i) {
        int s = src[ebase + i * 256 + t];
        atomicAdd(&h[s >> 9], 1);
    }
    __syncthreads();
    if (t < NB) histG[bid * NB + t] = h[t];
}

// scan histG -> per-(block,graph) global bases + per-graph bases. 1 block, 1024 threads.
__global__ __launch_bounds__(1024) void k_scanG(const int* __restrict__ histG,
                                                int* __restrict__ startG,
                                                int* __restrict__ gbase) {
    __shared__ int csum[16][64];
    __shared__ int gpre[64];
    int t = threadIdx.x;
    int g = t & 63, c = t >> 6;  // 16 chunks of 16 blocks
    int vals[16];
    int s = 0;
    #pragma unroll
    for (int i = 0; i < 16; ++i) {
        vals[i] = histG[(c * 16 + i) * NB + g];
        s += vals[i];
    }
    csum[c][g] = s;
    __syncthreads();
    int pre = 0;
    for (int i = 0; i < c; ++i) pre += csum[i][g];
    if (c == 0) {
        int tot = 0;
        #pragma unroll
        for (int i = 0; i < 16; ++i) tot += csum[i][g];
        int x = tot;
        #pragma unroll
        for (int o = 1; o < 64; o <<= 1) {
            int y = __shfl_up(x, o);
            if (g >= o) x += y;
        }
        gpre[g] = x - tot;
        gbase[g] = x - tot;
        if (g == 63) gbase[64] = x;  // == NE
    }
    __syncthreads();
    int run = gpre[g] + pre;
    #pragma unroll
    for (int i = 0; i < 16; ++i) {
        startG[(c * 16 + i) * NB + g] = run;
        run += vals[i];
    }
}

// LDS-staged graph-sort of each 4096-edge chunk -> coalesced writes into
// graph-contiguous tmp. Record: {src_local | dst_local<<9, w_bits}.
__global__ __launch_bounds__(256) void k_scatterA(
        const int* __restrict__ src, const int* __restrict__ dst,
        const float* __restrict__ ew, const int* __restrict__ histG,
        const int* __restrict__ startG, int2* __restrict__ tmp) {
    __shared__ int lstart[NB + 1];
    __shared__ int cursor[NB];
    __shared__ int gdst[NB];
    __shared__ int2 buf[EPB];   // 32 KB
    int t = threadIdx.x, bid = blockIdx.x;
    if (t < NB) {
        int c = histG[bid * NB + t];
        int x = c;
        #pragma unroll
        for (int o = 1; o < 64; o <<= 1) {
            int y = __shfl_up(x, o);
            if (t >= o) x += y;
        }
        lstart[t] = x - c;
        cursor[t] = x - c;
        gdst[t] = startG[bid * NB + t];
        if (t == 63) lstart[NB] = x;  // == EPB
    }
    __syncthreads();
    int ebase = bid * EPB;
    #pragma unroll
    for (int i = 0; i < EPB / 256; ++i) {
        int e = ebase + i * 256 + t;
        int s = src[e], d = dst[e];
        float w = ew[e];
        int g = s >> 9;
        int meta = (s & 511) | ((d & 511) << 9);
        int p = atomicAdd(&cursor[g], 1);
        buf[p] = make_int2(meta, __float_as_int(w));
    }
    __syncthreads();
    for (int g = 0; g < NB; ++g) {
        int lo = lstart[g], hi = lstart[g + 1];
        int base = gdst[g];
        for (int i = lo + t; i < hi; i += 256) tmp[base + (i - lo)] = buf[i];
    }
}

// per-graph counting sort by dst (2 blocks/graph). Emits final CSR + offs.
__global__ __launch_bounds__(512) void k_sortB(
        const int2* __restrict__ tmp, const int* __restrict__ gbase,
        int2* __restrict__ sorted, int* __restrict__ offs) {
    __shared__ int hist[NP];
    __shared__ int start[NP + 1];
    __shared__ int cursor[NP / 2];
    __shared__ int perm[CAPH];   // 34 KB
    int t = threadIdx.x;
    int g = blockIdx.x >> 1, half = blockIdx.x & 1;
    int gbeg = gbase[g], gend = gbase[g + 1];
    int cnt = gend - gbeg;
    if (t < NP) hist[t] = 0;
    __syncthreads();
    for (int i = t; i < cnt; i += 512) {
        int meta = tmp[gbeg + i].x;
        atomicAdd(&hist[(meta >> 9) & 511], 1);
    }
    __syncthreads();
    if (t < NP) start[t] = hist[t];
    __syncthreads();
    for (int o = 1; o < NP; o <<= 1) {
        int v = 0;
        if (t >= o && t < NP) v = start[t - o];
        __syncthreads();
        if (t < NP) start[t] += v;
        __syncthreads();
    }
    if (t < NP) start[t] -= hist[t];
    if (t == 0) start[NP] = cnt;
    __syncthreads();
    int h0 = half * 256;
    if (t < 256) {
        int n = h0 + t;
        offs[g * NP + n] = gbeg + start[n];
        cursor[t] = start[n];
    }
    if (blockIdx.x == 0 && t == 0) offs[NN] = NE;
    __syncthreads();
    int ha = start[h0];
    int hb = half ? cnt : start[256];
    for (int i = t; i < cnt; i += 512) {
        int meta = tmp[gbeg + i].x;
        int d = (meta >> 9) & 511;
        if ((d >> 8) == half) {
            int p = atomicAdd(&cursor[d - h0], 1);
            perm[p - ha] = i;
        }
    }
    __syncthreads();
    for (int o = ha + t; o < hb; o += 512) {
        sorted[gbeg + o] = tmp[gbeg + perm[o - ha]];
    }
}

// agg[node,h] = sum_{e in CSR[node]} w_e * x[src_e, h]    (block = 1 node, 128 threads)
__global__ void k_agg(const float* __restrict__ x, const int* __restrict__ offs,
                      const int2* __restrict__ rec, float* __restrict__ agg) {
    int bid = blockIdx.x;
    int node = (bid & 7) * (NN / 8) + (bid >> 3);  // XCD-locality swizzle
    int h = threadIdx.x;
    int sbase = node & ~(NP - 1);
    int beg = offs[node], end = offs[node + 1];
    float acc = 0.f;
    int j = beg;
    for (; j + 4 <= end; j += 4) {
        int2 r0 = rec[j], r1 = rec[j + 1], r2 = rec[j + 2], r3 = rec[j + 3];
        float v0 = x[(size_t)(sbase + (r0.x & 511)) * H + h];
        float v1 = x[(size_t)(sbase + (r1.x & 511)) * H + h];
        float v2 = x[(size_t)(sbase + (r2.x & 511)) * H + h];
        float v3 = x[(size_t)(sbase + (r3.x & 511)) * H + h];
        acc += __int_as_float(r0.y) * v0;
        acc += __int_as_float(r1.y) * v1;
        acc += __int_as_float(r2.y) * v2;
        acc += __int_as_float(r3.y) * v3;
    }
    for (; j < end; ++j)
        acc += __int_as_float(rec[j].y) * x[(size_t)(sbase + (rec[j].x & 511)) * H + h];
    agg[(size_t)node * H + h] = acc;
}

// Y = [Amat|Xmat] @ [Wrel;Wroot] + brel ; fused BN column partials (NSH shadows).
// Block: 32 rows x 128 cols, 256 threads, 4x4 per-thread tile. Grid NN/32=1024.
__global__ __launch_bounds__(256) void k_gemm(
        const float* Amat, const float* __restrict__ Xmat,
        const float* __restrict__ Wrel, const float* __restrict__ Wroot,
        const float* __restrict__ brel, float* Y,
        float* __restrict__ bn_base) {
    __shared__ float At[32][36];    // A tile transposed [k][row], padded (16B-aligned rows)
    __shared__ float Wt[32][128];   // W tile [k][col]
    __shared__ float colS[128], colQ[128];
    int tid = threadIdx.x;
    int tc = tid & 31;      // col group (4 cols)
    int tr = tid >> 5;      // row group (4 rows)
    int row0 = blockIdx.x * 32;
    float acc[4][4];
    #pragma unroll
    for (int r = 0; r < 4; ++r)
        #pragma unroll
        for (int c = 0; c < 4; ++c) acc[r][c] = 0.f;

    int arow = tid >> 3;         // 0..31
    int akq  = (tid & 7) * 4;    // k sub-offset
    int wk   = tid >> 5;         // 0..7
    int wcol = (tid & 31) * 4;

    for (int k0 = 0; k0 < 2 * H; k0 += 32) {
        const float* A = (k0 < H) ? Amat : Xmat;
        const float* __restrict__ W = (k0 < H) ? Wrel : Wroot;
        int kb = k0 & (H - 1);
        __syncthreads();
        float4 a4 = *(const float4*)&A[(size_t)(row0 + arow) * H + kb + akq];
        At[akq + 0][arow] = a4.x;
        At[akq + 1][arow] = a4.y;
        At[akq + 2][arow] = a4.z;
        At[akq + 3][arow] = a4.w;
        #pragma unroll
        for (int i = 0; i < 4; ++i) {
            int k = wk + 8 * i;
            *(float4*)&Wt[k][wcol] = *(const float4*)&W[(size_t)(kb + k) * H + wcol];
        }
        __syncthreads();
        #pragma unroll
        for (int k = 0; k < 32; ++k) {
            float4 a = *(const float4*)&At[k][tr * 4];
            float4 w = *(const float4*)&Wt[k][tc * 4];
            float av[4] = {a.x, a.y, a.z, a.w};
            float wv[4] = {w.x, w.y, w.z, w.w};
            #pragma unroll
            for (int r = 0; r < 4; ++r)
                #pragma unroll
                for (int c = 0; c < 4; ++c) acc[r][c] += av[r] * wv[c];
        }
    }
    // epilogue: bias, store, BN partials
    float bb[4];
    #pragma unroll
    for (int c = 0; c < 4; ++c) bb[c] = brel[tc * 4 + c];
    float ls[4] = {0, 0, 0, 0}, lq[4] = {0, 0, 0, 0};
    #pragma unroll
    for (int r = 0; r < 4; ++r) {
        int row = row0 + tr * 4 + r;
        float v0 = acc[r][0] + bb[0], v1 = acc[r][1] + bb[1];
        float v2 = acc[r][2] + bb[2], v3 = acc[r][3] + bb[3];
        float4 o; o.x = v0; o.y = v1; o.z = v2; o.w = v3;
        *(float4*)&Y[(size_t)row * H + tc * 4] = o;
        ls[0] += v0; lq[0] += v0 * v0;
        ls[1] += v1; lq[1] += v1 * v1;
        ls[2] += v2; lq[2] += v2 * v2;
        ls[3] += v3; lq[3] += v3 * v3;
    }
    __syncthreads();
    if (tid < 128) { colS[tid] = 0.f; colQ[tid] = 0.f; }
    __syncthreads();
    #pragma unroll
    for (int c = 0; c < 4; ++c) {
        atomicAdd(&colS[tc * 4 + c], ls[c]);
        atomicAdd(&colQ[tc * 4 + c], lq[c]);
    }
    __syncthreads();
    if (tid < 128) {
        int sh = blockIdx.x & (NSH - 1);
        atomicAdd(&bn_base[(sh * 2 + 0) * H + tid], colS[tid]);
        atomicAdd(&bn_base[(sh * 2 + 1) * H + tid], colQ[tid]);
    }
}

__global__ void k_bnfinal(const float* __restrict__ bn_base, const float* __restrict__ g,
                          const float* __restrict__ be, float* __restrict__ sc_sh) {
    int t = threadIdx.x;
    float su = 0.f, sq = 0.f;
    #pragma unroll
    for (int sh = 0; sh < NSH; ++sh) {
        su += bn_base[(sh * 2 + 0) * H + t];
        sq += bn_base[(sh * 2 + 1) * H + t];
    }
    float mu = su * (1.f / NN);
    float var = sq * (1.f / NN) - mu * mu;
    float sc = rsqrtf(var + BN_EPS) * g[t];
    sc_sh[t] = sc;
    sc_sh[H + t] = be[t] - mu * sc;
}

// in-place x = relu(y*scale + shift), float4 (layer 1)
__global__ void k_bnrelu(float* __restrict__ y, const float* __restrict__ sc_sh) {
    int idx = blockIdx.x * 256 + threadIdx.x;
    int c = (idx & 31) * 4;
    float4 v = ((const float4*)y)[idx];
    float4 sc = *(const float4*)&sc_sh[c];
    float4 sh = *(const float4*)&sc_sh[H + c];
    v.x = fmaxf(fmaf(v.x, sc.x, sh.x), 0.f);
    v.y = fmaxf(fmaf(v.y, sc.y, sh.y), 0.f);
    v.z = fmaxf(fmaf(v.z, sc.z, sh.z), 0.f);
    v.w = fmaxf(fmaf(v.w, sc.w, sh.w), 0.f);
    ((float4*)y)[idx] = v;
}

// layer 2: BN+ReLU fused with s = softmax(x @ W_pool + b_pool).
// 32-thread groups own one node row (128 floats = 32 float4).
__global__ void k_bnrelu_s(float* __restrict__ y, const float* __restrict__ sc_sh,
                           const float* __restrict__ Wp, const float* __restrict__ bp,
                           float* __restrict__ s) {
    int tid = threadIdx.x;
    int idx = blockIdx.x * 256 + tid;
    int c = (idx & 31) * 4;
    float4 v = ((const float4*)y)[idx];
    float4 sc = *(const float4*)&sc_sh[c];
    float4 sh = *(const float4*)&sc_sh[H + c];
    v.x = fmaxf(fmaf(v.x, sc.x, sh.x), 0.f);
    v.y = fmaxf(fmaf(v.y, sc.y, sh.y), 0.f);
    v.z = fmaxf(fmaf(v.z, sc.z, sh.z), 0.f);
    v.w = fmaxf(fmaf(v.w, sc.w, sh.w), 0.f);
    ((float4*)y)[idx] = v;
    float z0 = v.x * Wp[c * 2 + 0] + v.y * Wp[(c + 1) * 2 + 0]
             + v.z * Wp[(c + 2) * 2 + 0] + v.w * Wp[(c + 3) * 2 + 0];
    float z1 = v.x * Wp[c * 2 + 1] + v.y * Wp[(c + 1) * 2 + 1]
             + v.z * Wp[(c + 2) * 2 + 1] + v.w * Wp[(c + 3) * 2 + 1];
    #pragma unroll
    for (int o = 16; o; o >>= 1) { z0 += __shfl_down(z0, o); z1 += __shfl_down(z1, o); }
    if ((tid & 31) == 0) {
        int row = idx >> 5;
        z0 += bp[0]; z1 += bp[1];
        float m = fmaxf(z0, z1);
        float e0 = expf(z0 - m), e1 = expf(z1 - m);
        float inv = 1.f / (e0 + e1);
        s[row * 2] = e0 * inv;
        s[row * 2 + 1] = e1 * inv;
    }
}

// pool[b,k,h] += sum_n s[n,k]*x[n,h]   (block = 64-node chunk of one graph)
__global__ void k_pool_out(const float* __restrict__ x, const float* __restrict__ s,
                           float* __restrict__ pool) {
    int b = blockIdx.x & 63, chunk = blockIdx.x >> 6;
    int h = threadIdx.x;
    float a0 = 0.f, a1 = 0.f;
    int n0 = b * NP + chunk * 64;
    for (int i = 0; i < 64; ++i) {
        float2 sv = ((const float2*)s)[n0 + i];
        float xv = x[(size_t)(n0 + i) * H + h];
        a0 += sv.x * xv;
        a1 += sv.y * xv;
    }
    atomicAdd(&pool[(b * 2 + 0) * H + h], a0);
    atomicAdd(&pool[(b * 2 + 1) * H + h], a1);
}

// per-edge stats (+ fused per-graph node stats on q==0 blocks).
__global__ __launch_bounds__(256) void k_edge_stats(
        const int2* __restrict__ sorted, const int* __restrict__ gbase,
        const float* __restrict__ s, float* __restrict__ num, float* __restrict__ den,
        float* __restrict__ gst) {
    __shared__ float2 sl[NP];
    __shared__ float ln[4], ld2[4];
    int t = threadIdx.x;
    int g = blockIdx.x >> 2, q = blockIdx.x & 3;
    int gbeg = gbase[g], gend = gbase[g + 1];
    for (int i = t; i < NP; i += 256) sl[i] = ((const float2*)s)[g * NP + i];
    __syncthreads();
    float an = 0.f, ad = 0.f;
    int cnt = gend - gbeg;
    int q0 = gbeg + (cnt * q) / 4, q1 = gbeg + (cnt * (q + 1)) / 4;
    for (int i = q0 + t; i < q1; i += 256) {
        int2 r = sorted[i];
        float w = __int_as_float(r.y);
        float2 ss = sl[r.x & 511];
        float2 sd = sl[(r.x >> 9) & 511];
        an += w * (ss.x * sd.x + ss.y * sd.y);
        ad += w * (ss.x * ss.x + ss.y * ss.y);
    }
    for (int o = 32; o; o >>= 1) { an += __shfl_down(an, o); ad += __shfl_down(ad, o); }
    if ((t & 63) == 0) { ln[t >> 6] = an; ld2[t >> 6] = ad; }
    __syncthreads();
    if (t == 0) {
        atomicAdd(&num[g], ln[0] + ln[1] + ln[2] + ln[3]);
        atomicAdd(&den[g], ld2[0] + ld2[1] + ld2[2] + ld2[3]);
    }
    if (q == 0) {  // fused graph stats from staged sl
        float p00 = 0.f, p01 = 0.f, p11 = 0.f;
        for (int i = t; i < NP; i += 256) {
            float2 sv = sl[i];
            p00 += sv.x * sv.x;
            p01 += sv.x * sv.y;
            p11 += sv.y * sv.y;
        }
        for (int o = 32; o; o >>= 1) {
            p00 += __shfl_down(p00, o);
            p01 += __shfl_down(p01, o);
            p11 += __shfl_down(p11, o);
        }
        __shared__ float tp[3][4];
        if ((t & 63) == 0) {
            int w = t >> 6;
            tp[0][w] = p00; tp[1][w] = p01; tp[2][w] = p11;
        }
        __syncthreads();
        if (t == 0) {
            gst[g] = tp[0][0] + tp[0][1] + tp[0][2] + tp[0][3];
            gst[NB + g] = tp[1][0] + tp[1][1] + tp[1][2] + tp[1][3];
            gst[2 * NB + g] = tp[2][0] + tp[2][1] + tp[2][2] + tp[2][3];
        }
    }
}

// bid<64: logits for graph bid ; bid==64: losses
__global__ void k_logits_losses(const float* __restrict__ pool, const float* __restrict__ Wpost,
                                const float* __restrict__ bpost, const float* __restrict__ num,
                                const float* __restrict__ den, const float* __restrict__ gst,
                                float* __restrict__ out) {
    int t = threadIdx.x;
    if (blockIdx.x < 64) {
        int b = blockIdx.x;
        float v = pool[b * 256 + t];
        v = v > 0.f ? v : 0.f;
        float p0 = v * Wpost[t * 2], p1 = v * Wpost[t * 2 + 1];
        for (int o = 32; o; o >>= 1) { p0 += __shfl_down(p0, o); p1 += __shfl_down(p1, o); }
        __shared__ float t0[4], t1[4];
        if ((t & 63) == 0) { t0[t >> 6] = p0; t1[t >> 6] = p1; }
        __syncthreads();
        if (t == 0) {
            out[b * 2] = t0[0] + t0[1] + t0[2] + t0[3] + bpost[0];
            out[b * 2 + 1] = t1[0] + t1[1] + t1[2] + t1[3] + bpost[1];
        }
    } else if (t < 64) {
        float s00 = gst[t], s01 = gst[NB + t], s11 = gst[2 * NB + t];
        float mc = -(num[t] / den[t]);
        float nrm = sqrtf(s00 * s00 + 2.f * s01 * s01 + s11 * s11);
        const float a = 0.70710678118654752440f;  // 1/sqrt(2)
        float d00 = s00 / nrm - a, d01 = s01 / nrm, d11 = s11 / nrm - a;
        float ol = sqrtf(d00 * d00 + 2.f * d01 * d01 + d11 * d11);
        for (int o = 32; o; o >>= 1) { mc += __shfl_down(mc, o); ol += __shfl_down(ol, o); }
        if (t == 0) {
            out[NB * 2] = mc * (1.f / NB);
            out[NB * 2 + 1] = ol * (1.f / NB);
        }
    }
}

// ---------------- launch ----------------
extern "C" void kernel_launch(void* const* d_in, const int* in_sizes, int n_in,
                              void* d_out, int out_size, void* d_ws, size_t ws_size,
                              hipStream_t stream) {
    const float* nf     = (const float*)d_in[0];
    const int*   ei     = (const int*)d_in[1];
    const float* ew     = (const float*)d_in[2];
    const float* W_pre  = (const float*)d_in[4];
    const float* b_pre  = (const float*)d_in[5];
    const float* W1_rel = (const float*)d_in[6];
    const float* b1_rel = (const float*)d_in[7];
    const float* W1_root= (const float*)d_in[8];
    const float* g1     = (const float*)d_in[9];
    const float* be1    = (const float*)d_in[10];
    const float* W2_rel = (const float*)d_in[11];
    const float* b2_rel = (const float*)d_in[12];
    const float* W2_root= (const float*)d_in[13];
    const float* g2     = (const float*)d_in[14];
    const float* be2    = (const float*)d_in[15];
    const float* W_pool = (const float*)d_in[16];
    const float* b_pool = (const float*)d_in[17];
    const float* W_post = (const float*)d_in[18];
    const float* b_post = (const float*)d_in[19];

    char* ws = (char*)d_ws;
    float* bufA   = (float*)(ws + OFF_BUFA);
    float* bufB   = (float*)(ws + OFF_BUFB);
    int2*  tmp    = (int2*)(ws + OFF_TMP);
    int2*  sorted = (int2*)(ws + OFF_SORT);
    int*   offs   = (int*)(ws + OFF_OFFS);
    int*   histG  = (int*)(ws + OFF_HISTG);
    int*   startG = (int*)(ws + OFF_STARTG);
    int*   gbase  = (int*)(ws + OFF_GBASE);
    float* sarr   = (float*)(ws + OFF_S);
    float* scsh   = (float*)(ws + OFF_SCSH);
    float* gst    = (float*)(ws + OFF_GST);
    float* numA   = (float*)(ws + OFF_NUM);
    float* denA   = (float*)(ws + OFF_DEN);
    float* bn     = (float*)(ws + OFF_BN);
    float* pool   = (float*)(ws + OFF_POOL);
    float* outF   = (float*)d_out;

    const int* srcA = ei;
    const int* dstA = ei + NE;
    float* bn1 = bn;
    float* bn2 = (float*)(ws + OFF_BN + SZ_BNL);

    hipMemsetAsync(ws + OFF_ZERO, 0, ZERO_BYTES, stream);

    // edge sort pipeline (coalesced writes only)
    k_pre<<<NN / 8, 128, 0, stream>>>(nf, W_pre, b_pre, bufA);
    k_hist<<<NBLK, 256, 0, stream>>>(srcA, histG);
    k_scanG<<<1, 1024, 0, stream>>>(histG, startG, gbase);
    k_scatterA<<<NBLK, 256, 0, stream>>>(srcA, dstA, ew, histG, startG, tmp);
    k_sortB<<<2 * NB, 512, 0, stream>>>(tmp, gbase, sorted, offs);

    // layer 1
    k_agg<<<NN, 128, 0, stream>>>(bufA, offs, sorted, bufB);
    k_gemm<<<NN / 32, 256, 0, stream>>>(bufB, bufA, W1_rel, W1_root, b1_rel, bufB, bn1);
    k_bnfinal<<<1, H, 0, stream>>>(bn1, g1, be1, scsh);
    k_bnrelu<<<(NN * H / 4) / 256, 256, 0, stream>>>(bufB, scsh);

    // layer 2
    k_agg<<<NN, 128, 0, stream>>>(bufB, offs, sorted, bufA);
    k_gemm<<<NN / 32, 256, 0, stream>>>(bufA, bufB, W2_rel, W2_root, b2_rel, bufA, bn2);
    k_bnfinal<<<1, H, 0, stream>>>(bn2, g2, be2, scsh + 2 * H);
    k_bnrelu_s<<<(NN * H / 4) / 256, 256, 0, stream>>>(bufA, scsh + 2 * H,
                                                       W_pool, b_pool, sarr);

    // pooling + losses
    k_pool_out<<<8 * NB, 128, 0, stream>>>(bufA, sarr, pool);
    k_edge_stats<<<4 * NB, 256, 0, stream>>>(sorted, gbase, sarr, numA, denA, gst);
    k_logits_losses<<<NB + 1, 256, 0, stream>>>(pool, W_post, b_post, numA, denA, gst, outF);
}

// Round 5
// 297.469 us; speedup vs baseline: 2.1539x; 1.1946x over previous
//
#include <hip/hip_runtime.h>

#define NN 32768      // total nodes
#define NP 512        // nodes per graph
#define NB 64         // graphs
#define NE 1048576    // edges
#define FIN 16
#define H 128
#define BN_EPS 1e-5f
#define EPB 4096      // edges per hist/scatterA block
#define NBLK (NE / EPB)   // 256
#define CAPH 8704     // max edges per half-graph
#define NSH 16        // BN shadow copies

typedef unsigned int u32;
typedef unsigned short u16;
typedef __attribute__((ext_vector_type(8))) short bf16x8;
typedef __attribute__((ext_vector_type(4))) float f32x4;

__device__ __forceinline__ u16 f2bf(float f) {
    u32 u = __float_as_uint(f);
    return (u16)((u + 0x7fffu + ((u >> 16) & 1u)) >> 16);
}
__device__ __forceinline__ float bfLo(u32 p) { return __uint_as_float(p << 16); }
__device__ __forceinline__ float bfHi(u32 p) { return __uint_as_float(p & 0xffff0000u); }
__device__ __forceinline__ float b2f(u16 v) { return __uint_as_float((u32)v << 16); }

// ---------------- workspace layout (bytes) ----------------
static constexpr size_t SZ_HALF   = (size_t)NN * H * 2;            // 8 MiB (bf16 act)
static constexpr size_t OFF_X     = 0;                             // x0/x1/x2 chain
static constexpr size_t OFF_AGG   = OFF_X + SZ_HALF;               // agg bf16 (aliases tmp)
static constexpr size_t OFF_TMP   = OFF_AGG;                       // int2 tmp (8 MiB)
static constexpr size_t OFF_SORT  = OFF_AGG + SZ_HALF;             // NE int2 (8 MiB)
static constexpr size_t OFF_OFFS  = OFF_SORT + (size_t)NE * 8;     // NN+8 ints
static constexpr size_t OFF_HISTG = OFF_OFFS + ((size_t)NN + 128) * 4;
static constexpr size_t OFF_STARTG= OFF_HISTG + (size_t)NBLK * NB * 4;
static constexpr size_t OFF_GBASE = OFF_STARTG + (size_t)NBLK * NB * 4;  // 65 ints
static constexpr size_t OFF_WT1   = OFF_GBASE + 512;               // 128*256 bf16 = 64 KiB
static constexpr size_t OFF_WT2   = OFF_WT1 + (size_t)H * 2 * H * 2;
static constexpr size_t OFF_S     = OFF_WT2 + (size_t)H * 2 * H * 2;   // NN*2 f32
static constexpr size_t OFF_SCSH  = OFF_S + (size_t)NN * 2 * 4;    // 4*H f32
static constexpr size_t OFF_GST   = OFF_SCSH + 4 * H * 4;          // 3*NB f32
// --- zeroed region (one memset) ---
static constexpr size_t OFF_ZERO  = OFF_GST + 1024;
static constexpr size_t OFF_NUM   = OFF_ZERO;                      // NB f32
static constexpr size_t OFF_DEN   = OFF_NUM + 256;                 // NB f32
static constexpr size_t OFF_BN    = OFF_DEN + 256;                 // 2 layers * NSH * 2 * H f32
static constexpr size_t SZ_BNL    = (size_t)NSH * 2 * H * 4;
static constexpr size_t OFF_POOL  = OFF_BN + 2 * SZ_BNL;           // NB*2*H f32
static constexpr size_t ZERO_BYTES= (OFF_POOL + (size_t)NB * 2 * H * 4) - OFF_ZERO;

// ---------------- kernels ----------------

// x0 = node_feature @ W_pre + b_pre -> bf16   (8 nodes per 128-thread block)
__global__ void k_pre(const float* __restrict__ nf, const float* __restrict__ Wp,
                      const float* __restrict__ bp, u16* __restrict__ x0) {
    __shared__ float sW[FIN * H];
    __shared__ float sNF[8 * FIN];
    int tid = threadIdx.x;
    for (int i = tid; i < FIN * H; i += 128) sW[i] = Wp[i];
    int n0 = blockIdx.x * 8;
    sNF[tid] = nf[n0 * FIN + tid];
    __syncthreads();
    float b = bp[tid];
    #pragma unroll
    for (int r = 0; r < 8; ++r) {
        float acc = b;
        #pragma unroll
        for (int f = 0; f < FIN; ++f) acc += sNF[r * FIN + f] * sW[f * H + tid];
        x0[(size_t)(n0 + r) * H + tid] = f2bf(acc);
    }
}

// stacked transposed weight -> bf16: WT[c][k] = (k<H ? Wrel[k][c] : Wroot[k-H][c])
__global__ void k_wprep(const float* __restrict__ Wrel, const float* __restrict__ Wroot,
                        u16* __restrict__ WT) {
    int i = blockIdx.x * 256 + threadIdx.x;   // over H*2H
    int c = i >> 8, k = i & 255;
    float v = (k < H) ? Wrel[k * H + c] : Wroot[(k - H) * H + c];
    WT[c * 256 + k] = f2bf(v);
}

// per-block histogram of edges by graph
__global__ __launch_bounds__(256) void k_hist(const int* __restrict__ src,
                                              int* __restrict__ histG) {
    __shared__ int h[NB];
    int t = threadIdx.x, bid = blockIdx.x;
    if (t < NB) h[t] = 0;
    __syncthreads();
    int ebase = bid * EPB;
    #pragma unroll
    for (int i = 0; i < EPB / 256; ++i) {
        int s = src[ebase + i * 256 + t];
        atomicAdd(&h[s >> 9], 1);
    }
    __syncthreads();
    if (t < NB) histG[bid * NB + t] = h[t];
}

// scan histG -> per-(block,graph) global bases + per-graph bases. 1 block, 1024 threads.
__global__ __launch_bounds__(1024) void k_scanG(const int* __restrict__ histG,
                                                int* __restrict__ startG,
                                                int* __restrict__ gbase) {
    __shared__ int csum[16][64];
    __shared__ int gpre[64];
    int t = threadIdx.x;
    int g = t & 63, c = t >> 6;
    int vals[16];
    int s = 0;
    #pragma unroll
    for (int i = 0; i < 16; ++i) {
        vals[i] = histG[(c * 16 + i) * NB + g];
        s += vals[i];
    }
    csum[c][g] = s;
    __syncthreads();
    int pre = 0;
    for (int i = 0; i < c; ++i) pre += csum[i][g];
    if (c == 0) {
        int tot = 0;
        #pragma unroll
        for (int i = 0; i < 16; ++i) tot += csum[i][g];
        int x = tot;
        #pragma unroll
        for (int o = 1; o < 64; o <<= 1) {
            int y = __shfl_up(x, o);
            if (g >= o) x += y;
        }
        gpre[g] = x - tot;
        gbase[g] = x - tot;
        if (g == 63) gbase[64] = x;
    }
    __syncthreads();
    int run = gpre[g] + pre;
    #pragma unroll
    for (int i = 0; i < 16; ++i) {
        startG[(c * 16 + i) * NB + g] = run;
        run += vals[i];
    }
}

// LDS-staged graph-sort of each 4096-edge chunk -> coalesced writes.
__global__ __launch_bounds__(256) void k_scatterA(
        const int* __restrict__ src, const int* __restrict__ dst,
        const float* __restrict__ ew, const int* __restrict__ histG,
        const int* __restrict__ startG, int2* __restrict__ tmp) {
    __shared__ int lstart[NB + 1];
    __shared__ int cursor[NB];
    __shared__ int gdst[NB];
    __shared__ int2 buf[EPB];   // 32 KB
    int t = threadIdx.x, bid = blockIdx.x;
    if (t < NB) {
        int c = histG[bid * NB + t];
        int x = c;
        #pragma unroll
        for (int o = 1; o < 64; o <<= 1) {
            int y = __shfl_up(x, o);
            if (t >= o) x += y;
        }
        lstart[t] = x - c;
        cursor[t] = x - c;
        gdst[t] = startG[bid * NB + t];
        if (t == 63) lstart[NB] = x;
    }
    __syncthreads();
    int ebase = bid * EPB;
    #pragma unroll
    for (int i = 0; i < EPB / 256; ++i) {
        int e = ebase + i * 256 + t;
        int s = src[e], d = dst[e];
        float w = ew[e];
        int g = s >> 9;
        int meta = (s & 511) | ((d & 511) << 9);
        int p = atomicAdd(&cursor[g], 1);
        buf[p] = make_int2(meta, __float_as_int(w));
    }
    __syncthreads();
    for (int g = 0; g < NB; ++g) {
        int lo = lstart[g], hi = lstart[g + 1];
        int base = gdst[g];
        for (int i = lo + t; i < hi; i += 256) tmp[base + (i - lo)] = buf[i];
    }
}

// per-graph counting sort by dst (2 blocks/graph). Emits final CSR + offs.
__global__ __launch_bounds__(512) void k_sortB(
        const int2* __restrict__ tmp, const int* __restrict__ gbase,
        int2* __restrict__ sorted, int* __restrict__ offs) {
    __shared__ int hist[NP];
    __shared__ int start[NP + 1];
    __shared__ int cursor[NP / 2];
    __shared__ int perm[CAPH];   // 34 KB
    int t = threadIdx.x;
    int g = blockIdx.x >> 1, half = blockIdx.x & 1;
    int gbeg = gbase[g], gend = gbase[g + 1];
    int cnt = gend - gbeg;
    if (t < NP) hist[t] = 0;
    __syncthreads();
    for (int i = t; i < cnt; i += 512) {
        int meta = tmp[gbeg + i].x;
        atomicAdd(&hist[(meta >> 9) & 511], 1);
    }
    __syncthreads();
    if (t < NP) start[t] = hist[t];
    __syncthreads();
    for (int o = 1; o < NP; o <<= 1) {
        int v = 0;
        if (t >= o && t < NP) v = start[t - o];
        __syncthreads();
        if (t < NP) start[t] += v;
        __syncthreads();
    }
    if (t < NP) start[t] -= hist[t];
    if (t == 0) start[NP] = cnt;
    __syncthreads();
    int h0 = half * 256;
    if (t < 256) {
        int n = h0 + t;
        offs[g * NP + n] = gbeg + start[n];
        cursor[t] = start[n];
    }
    if (blockIdx.x == 0 && t == 0) offs[NN] = NE;
    __syncthreads();
    int ha = start[h0];
    int hb = half ? cnt : start[256];
    for (int i = t; i < cnt; i += 512) {
        int meta = tmp[gbeg + i].x;
        int d = (meta >> 9) & 511;
        if ((d >> 8) == half) {
            int p = atomicAdd(&cursor[d - h0], 1);
            perm[p - ha] = i;
        }
    }
    __syncthreads();
    for (int o = ha + t; o < hb; o += 512) {
        sorted[gbeg + o] = tmp[gbeg + perm[o - ha]];
    }
}

// agg[node,:] = sum_e w_e * x[src_e,:]  (bf16 in/out, fp32 acc; 1 wave per node,
// lane c handles cols 2c,2c+1). 256 threads = 4 nodes/block.
__global__ __launch_bounds__(256) void k_agg(const u16* __restrict__ x,
        const int* __restrict__ offs, const int2* __restrict__ rec,
        u16* __restrict__ agg) {
    int wv = threadIdx.x >> 6, lane = threadIdx.x & 63;
    int b = blockIdx.x;
    int swz = (b & 7) * (NN / 8 / 4) + (b >> 3);   // XCD-locality swizzle
    int node = swz * 4 + wv;
    int sbase = node & ~(NP - 1);
    const u16* xg = x + (size_t)sbase * H;
    int beg = offs[node], end = offs[node + 1];
    float a0 = 0.f, a1 = 0.f;
    int j = beg;
    for (; j + 4 <= end; j += 4) {
        int2 r0 = rec[j], r1 = rec[j + 1], r2 = rec[j + 2], r3 = rec[j + 3];
        u32 p0 = *(const u32*)(xg + (size_t)(r0.x & 511) * H + 2 * lane);
        u32 p1 = *(const u32*)(xg + (size_t)(r1.x & 511) * H + 2 * lane);
        u32 p2 = *(const u32*)(xg + (size_t)(r2.x & 511) * H + 2 * lane);
        u32 p3 = *(const u32*)(xg + (size_t)(r3.x & 511) * H + 2 * lane);
        float w0 = __int_as_float(r0.y), w1 = __int_as_float(r1.y);
        float w2 = __int_as_float(r2.y), w3 = __int_as_float(r3.y);
        a0 += w0 * bfLo(p0); a1 += w0 * bfHi(p0);
        a0 += w1 * bfLo(p1); a1 += w1 * bfHi(p1);
        a0 += w2 * bfLo(p2); a1 += w2 * bfHi(p2);
        a0 += w3 * bfLo(p3); a1 += w3 * bfHi(p3);
    }
    for (; j < end; ++j) {
        int2 r = rec[j];
        u32 p = *(const u32*)(xg + (size_t)(r.x & 511) * H + 2 * lane);
        float w = __int_as_float(r.y);
        a0 += w * bfLo(p); a1 += w * bfHi(p);
    }
    u32 packed = (u32)f2bf(a0) | ((u32)f2bf(a1) << 16);
    *(u32*)(agg + (size_t)node * H + 2 * lane) = packed;
}

// Y = [Amat|Xmat](bf16) @ WT^T(bf16) + brel via MFMA, fp32 acc.
// Block 256 thr / 4 waves, tile 64 rows x 128 cols x K=256. Y may alias Xmat.
__global__ __launch_bounds__(256) void k_gemm(
        const u16* __restrict__ Amat, const u16* Xmat,
        const u16* __restrict__ WT, const float* __restrict__ brel,
        u16* Y, float* __restrict__ bn_base) {
    __shared__ u16 sWT[128][264];          // [col][k], +8 pad (16B-aligned rows)
    __shared__ float colS[128], colQ[128];
    int tid = threadIdx.x;
    int w = tid >> 6, lane = tid & 63;
    int lr = lane & 15, lg = lane >> 4;
    int row0 = blockIdx.x * 64;
    int myrow = row0 + w * 16 + lr;

    // A fragments: issue all 8 global loads before LDS staging (latency overlap)
    bf16x8 af[8];
    const u16* pa = Amat + (size_t)myrow * H + lg * 8;
    const u16* px = Xmat + (size_t)myrow * H + lg * 8;
    #pragma unroll
    for (int kt = 0; kt < 4; ++kt) af[kt] = *(const bf16x8*)(pa + kt * 32);
    #pragma unroll
    for (int kt = 0; kt < 4; ++kt) af[4 + kt] = *(const bf16x8*)(px + kt * 32);

    // stage WT (64 KB) into LDS
    for (int i = tid; i < 128 * 32; i += 256) {
        int r = i >> 5, c = i & 31;
        *(uint4*)&sWT[r][c * 8] = *(const uint4*)(WT + r * 256 + c * 8);
    }
    if (tid < 128) { colS[tid] = 0.f; colQ[tid] = 0.f; }
    __syncthreads();

    f32x4 acc[8];
    #pragma unroll
    for (int nt = 0; nt < 8; ++nt) acc[nt] = (f32x4){0.f, 0.f, 0.f, 0.f};

    #pragma unroll
    for (int kt = 0; kt < 8; ++kt) {
        #pragma unroll
        for (int nt = 0; nt < 8; ++nt) {
            bf16x8 bf = *(const bf16x8*)&sWT[nt * 16 + lr][kt * 32 + lg * 8];
            acc[nt] = __builtin_amdgcn_mfma_f32_16x16x32_bf16(af[kt], bf, acc[nt], 0, 0, 0);
        }
    }

    // epilogue: bias, bf16 store, BN column partials
    float cs[8], cq[8];
    #pragma unroll
    for (int nt = 0; nt < 8; ++nt) {
        int col = nt * 16 + lr;
        float bias = brel[col];
        float s = 0.f, q = 0.f;
        #pragma unroll
        for (int j = 0; j < 4; ++j) {
            float v = acc[nt][j] + bias;
            int row = row0 + w * 16 + lg * 4 + j;
            Y[(size_t)row * H + col] = f2bf(v);
            s += v; q += v * v;
        }
        cs[nt] = s; cq[nt] = q;
    }
    #pragma unroll
    for (int nt = 0; nt < 8; ++nt) {
        cs[nt] += __shfl_xor(cs[nt], 16); cs[nt] += __shfl_xor(cs[nt], 32);
        cq[nt] += __shfl_xor(cq[nt], 16); cq[nt] += __shfl_xor(cq[nt], 32);
    }
    if (lg == 0) {
        #pragma unroll
        for (int nt = 0; nt < 8; ++nt) {
            atomicAdd(&colS[nt * 16 + lr], cs[nt]);
            atomicAdd(&colQ[nt * 16 + lr], cq[nt]);
        }
    }
    __syncthreads();
    if (tid < 128) {
        int sh = blockIdx.x & (NSH - 1);
        atomicAdd(&bn_base[(sh * 2 + 0) * H + tid], colS[tid]);
        atomicAdd(&bn_base[(sh * 2 + 1) * H + tid], colQ[tid]);
    }
}

__global__ void k_bnfinal(const float* __restrict__ bn_base, const float* __restrict__ g,
                          const float* __restrict__ be, float* __restrict__ sc_sh) {
    int t = threadIdx.x;
    float su = 0.f, sq = 0.f;
    #pragma unroll
    for (int sh = 0; sh < NSH; ++sh) {
        su += bn_base[(sh * 2 + 0) * H + t];
        sq += bn_base[(sh * 2 + 1) * H + t];
    }
    float mu = su * (1.f / NN);
    float var = sq * (1.f / NN) - mu * mu;
    float sc = rsqrtf(var + BN_EPS) * g[t];
    sc_sh[t] = sc;
    sc_sh[H + t] = be[t] - mu * sc;
}

// in-place bf16 x = relu(y*scale + shift); thread = 8 cols
__global__ void k_bnrelu(u16* __restrict__ y, const float* __restrict__ sc_sh) {
    int idx = blockIdx.x * 256 + threadIdx.x;    // NN*H/8 chunks
    int c = (idx & 15) * 8;
    uint4 u = ((const uint4*)y)[idx];
    u32 uu[4] = {u.x, u.y, u.z, u.w};
    u32 ro[4];
    #pragma unroll
    for (int p = 0; p < 4; ++p) {
        float v0 = fmaxf(fmaf(bfLo(uu[p]), sc_sh[c + 2 * p], sc_sh[H + c + 2 * p]), 0.f);
        float v1 = fmaxf(fmaf(bfHi(uu[p]), sc_sh[c + 2 * p + 1], sc_sh[H + c + 2 * p + 1]), 0.f);
        ro[p] = (u32)f2bf(v0) | ((u32)f2bf(v1) << 16);
    }
    uint4 o; o.x = ro[0]; o.y = ro[1]; o.z = ro[2]; o.w = ro[3];
    ((uint4*)y)[idx] = o;
}

// layer 2: BN+ReLU fused with s = softmax(x @ W_pool + b_pool); 16 thr per row
__global__ void k_bnrelu_s(u16* __restrict__ y, const float* __restrict__ sc_sh,
                           const float* __restrict__ Wp, const float* __restrict__ bp,
                           float* __restrict__ s) {
    int tid = threadIdx.x;
    int idx = blockIdx.x * 256 + tid;
    int c = (idx & 15) * 8;
    uint4 u = ((const uint4*)y)[idx];
    u32 uu[4] = {u.x, u.y, u.z, u.w};
    u32 ro[4];
    float z0 = 0.f, z1 = 0.f;
    #pragma unroll
    for (int p = 0; p < 4; ++p) {
        float v0 = fmaxf(fmaf(bfLo(uu[p]), sc_sh[c + 2 * p], sc_sh[H + c + 2 * p]), 0.f);
        float v1 = fmaxf(fmaf(bfHi(uu[p]), sc_sh[c + 2 * p + 1], sc_sh[H + c + 2 * p + 1]), 0.f);
        ro[p] = (u32)f2bf(v0) | ((u32)f2bf(v1) << 16);
        z0 += v0 * Wp[(c + 2 * p) * 2] + v1 * Wp[(c + 2 * p + 1) * 2];
        z1 += v0 * Wp[(c + 2 * p) * 2 + 1] + v1 * Wp[(c + 2 * p + 1) * 2 + 1];
    }
    uint4 o; o.x = ro[0]; o.y = ro[1]; o.z = ro[2]; o.w = ro[3];
    ((uint4*)y)[idx] = o;
    #pragma unroll
    for (int off = 8; off; off >>= 1) {
        z0 += __shfl_down(z0, off);
        z1 += __shfl_down(z1, off);
    }
    if ((tid & 15) == 0) {
        int row = idx >> 4;
        z0 += bp[0]; z1 += bp[1];
        float m = fmaxf(z0, z1);
        float e0 = expf(z0 - m), e1 = expf(z1 - m);
        float inv = 1.f / (e0 + e1);
        s[row * 2] = e0 * inv;
        s[row * 2 + 1] = e1 * inv;
    }
}

// pool[b,k,h] += sum_n s[n,k]*x[n,h]   (block = 64-node chunk of one graph)
__global__ void k_pool_out(const u16* __restrict__ x, const float* __restrict__ s,
                           float* __restrict__ pool) {
    int b = blockIdx.x & 63, chunk = blockIdx.x >> 6;
    int h = threadIdx.x;
    float a0 = 0.f, a1 = 0.f;
    int n0 = b * NP + chunk * 64;
    for (int i = 0; i < 64; ++i) {
        float2 sv = ((const float2*)s)[n0 + i];
        float xv = b2f(x[(size_t)(n0 + i) * H + h]);
        a0 += sv.x * xv;
        a1 += sv.y * xv;
    }
    atomicAdd(&pool[(b * 2 + 0) * H + h], a0);
    atomicAdd(&pool[(b * 2 + 1) * H + h], a1);
}

// per-edge stats (+ fused per-graph node stats on q==0 blocks).
__global__ __launch_bounds__(256) void k_edge_stats(
        const int2* __restrict__ sorted, const int* __restrict__ gbase,
        const float* __restrict__ s, float* __restrict__ num, float* __restrict__ den,
        float* __restrict__ gst) {
    __shared__ float2 sl[NP];
    __shared__ float ln[4], ld2[4];
    int t = threadIdx.x;
    int g = blockIdx.x >> 2, q = blockIdx.x & 3;
    int gbeg = gbase[g], gend = gbase[g + 1];
    for (int i = t; i < NP; i += 256) sl[i] = ((const float2*)s)[g * NP + i];
    __syncthreads();
    float an = 0.f, ad = 0.f;
    int cnt = gend - gbeg;
    int q0 = gbeg + (cnt * q) / 4, q1 = gbeg + (cnt * (q + 1)) / 4;
    for (int i = q0 + t; i < q1; i += 256) {
        int2 r = sorted[i];
        float w = __int_as_float(r.y);
        float2 ss = sl[r.x & 511];
        float2 sd = sl[(r.x >> 9) & 511];
        an += w * (ss.x * sd.x + ss.y * sd.y);
        ad += w * (ss.x * ss.x + ss.y * ss.y);
    }
    for (int o = 32; o; o >>= 1) { an += __shfl_down(an, o); ad += __shfl_down(ad, o); }
    if ((t & 63) == 0) { ln[t >> 6] = an; ld2[t >> 6] = ad; }
    __syncthreads();
    if (t == 0) {
        atomicAdd(&num[g], ln[0] + ln[1] + ln[2] + ln[3]);
        atomicAdd(&den[g], ld2[0] + ld2[1] + ld2[2] + ld2[3]);
    }
    if (q == 0) {
        float p00 = 0.f, p01 = 0.f, p11 = 0.f;
        for (int i = t; i < NP; i += 256) {
            float2 sv = sl[i];
            p00 += sv.x * sv.x;
            p01 += sv.x * sv.y;
            p11 += sv.y * sv.y;
        }
        for (int o = 32; o; o >>= 1) {
            p00 += __shfl_down(p00, o);
            p01 += __shfl_down(p01, o);
            p11 += __shfl_down(p11, o);
        }
        __shared__ float tp[3][4];
        if ((t & 63) == 0) {
            int w = t >> 6;
            tp[0][w] = p00; tp[1][w] = p01; tp[2][w] = p11;
        }
        __syncthreads();
        if (t == 0) {
            gst[g] = tp[0][0] + tp[0][1] + tp[0][2] + tp[0][3];
            gst[NB + g] = tp[1][0] + tp[1][1] + tp[1][2] + tp[1][3];
            gst[2 * NB + g] = tp[2][0] + tp[2][1] + tp[2][2] + tp[2][3];
        }
    }
}

// bid<64: logits for graph bid ; bid==64: losses
__global__ void k_logits_losses(const float* __restrict__ pool, const float* __restrict__ Wpost,
                                const float* __restrict__ bpost, const float* __restrict__ num,
                                const float* __restrict__ den, const float* __restrict__ gst,
                                float* __restrict__ out) {
    int t = threadIdx.x;
    if (blockIdx.x < 64) {
        int b = blockIdx.x;
        float v = pool[b * 256 + t];
        v = v > 0.f ? v : 0.f;
        float p0 = v * Wpost[t * 2], p1 = v * Wpost[t * 2 + 1];
        for (int o = 32; o; o >>= 1) { p0 += __shfl_down(p0, o); p1 += __shfl_down(p1, o); }
        __shared__ float t0[4], t1[4];
        if ((t & 63) == 0) { t0[t >> 6] = p0; t1[t >> 6] = p1; }
        __syncthreads();
        if (t == 0) {
            out[b * 2] = t0[0] + t0[1] + t0[2] + t0[3] + bpost[0];
            out[b * 2 + 1] = t1[0] + t1[1] + t1[2] + t1[3] + bpost[1];
        }
    } else if (t < 64) {
        float s00 = gst[t], s01 = gst[NB + t], s11 = gst[2 * NB + t];
        float mc = -(num[t] / den[t]);
        float nrm = sqrtf(s00 * s00 + 2.f * s01 * s01 + s11 * s11);
        const float a = 0.70710678118654752440f;
        float d00 = s00 / nrm - a, d01 = s01 / nrm, d11 = s11 / nrm - a;
        float ol = sqrtf(d00 * d00 + 2.f * d01 * d01 + d11 * d11);
        for (int o = 32; o; o >>= 1) { mc += __shfl_down(mc, o); ol += __shfl_down(ol, o); }
        if (t == 0) {
            out[NB * 2] = mc * (1.f / NB);
            out[NB * 2 + 1] = ol * (1.f / NB);
        }
    }
}

// ---------------- launch ----------------
extern "C" void kernel_launch(void* const* d_in, const int* in_sizes, int n_in,
                              void* d_out, int out_size, void* d_ws, size_t ws_size,
                              hipStream_t stream) {
    const float* nf     = (const float*)d_in[0];
    const int*   ei     = (const int*)d_in[1];
    const float* ew     = (const float*)d_in[2];
    const float* W_pre  = (const float*)d_in[4];
    const float* b_pre  = (const float*)d_in[5];
    const float* W1_rel = (const float*)d_in[6];
    const float* b1_rel = (const float*)d_in[7];
    const float* W1_root= (const float*)d_in[8];
    const float* g1     = (const float*)d_in[9];
    const float* be1    = (const float*)d_in[10];
    const float* W2_rel = (const float*)d_in[11];
    const float* b2_rel = (const float*)d_in[12];
    const float* W2_root= (const float*)d_in[13];
    const float* g2     = (const float*)d_in[14];
    const float* be2    = (const float*)d_in[15];
    const float* W_pool = (const float*)d_in[16];
    const float* b_pool = (const float*)d_in[17];
    const float* W_post = (const float*)d_in[18];
    const float* b_post = (const float*)d_in[19];

    char* ws = (char*)d_ws;
    u16*   bufX   = (u16*)(ws + OFF_X);
    u16*   bufAgg = (u16*)(ws + OFF_AGG);
    int2*  tmp    = (int2*)(ws + OFF_TMP);
    int2*  sorted = (int2*)(ws + OFF_SORT);
    int*   offs   = (int*)(ws + OFF_OFFS);
    int*   histG  = (int*)(ws + OFF_HISTG);
    int*   startG = (int*)(ws + OFF_STARTG);
    int*   gbase  = (int*)(ws + OFF_GBASE);
    u16*   WT1    = (u16*)(ws + OFF_WT1);
    u16*   WT2    = (u16*)(ws + OFF_WT2);
    float* sarr   = (float*)(ws + OFF_S);
    float* scsh   = (float*)(ws + OFF_SCSH);
    float* gst    = (float*)(ws + OFF_GST);
    float* numA   = (float*)(ws + OFF_NUM);
    float* denA   = (float*)(ws + OFF_DEN);
    float* bn     = (float*)(ws + OFF_BN);
    float* pool   = (float*)(ws + OFF_POOL);
    float* outF   = (float*)d_out;

    const int* srcA = ei;
    const int* dstA = ei + NE;
    float* bn1 = bn;
    float* bn2 = (float*)(ws + OFF_BN + SZ_BNL);

    hipMemsetAsync(ws + OFF_ZERO, 0, ZERO_BYTES, stream);

    k_pre<<<NN / 8, 128, 0, stream>>>(nf, W_pre, b_pre, bufX);
    k_wprep<<<(H * 2 * H) / 256, 256, 0, stream>>>(W1_rel, W1_root, WT1);
    k_wprep<<<(H * 2 * H) / 256, 256, 0, stream>>>(W2_rel, W2_root, WT2);
    k_hist<<<NBLK, 256, 0, stream>>>(srcA, histG);
    k_scanG<<<1, 1024, 0, stream>>>(histG, startG, gbase);
    k_scatterA<<<NBLK, 256, 0, stream>>>(srcA, dstA, ew, histG, startG, tmp);
    k_sortB<<<2 * NB, 512, 0, stream>>>(tmp, gbase, sorted, offs);

    // layer 1
    k_agg<<<NN / 4, 256, 0, stream>>>(bufX, offs, sorted, bufAgg);
    k_gemm<<<NN / 64, 256, 0, stream>>>(bufAgg, bufX, WT1, b1_rel, bufX, bn1);
    k_bnfinal<<<1, H, 0, stream>>>(bn1, g1, be1, scsh);
    k_bnrelu<<<(NN * H / 8) / 256, 256, 0, stream>>>(bufX, scsh);

    // layer 2
    k_agg<<<NN / 4, 256, 0, stream>>>(bufX, offs, sorted, bufAgg);
    k_gemm<<<NN / 64, 256, 0, stream>>>(bufAgg, bufX, WT2, b2_rel, bufX, bn2);
    k_bnfinal<<<1, H, 0, stream>>>(bn2, g2, be2, scsh + 2 * H);
    k_bnrelu_s<<<(NN * H / 8) / 256, 256, 0, stream>>>(bufX, scsh + 2 * H,
                                                       W_pool, b_pool, sarr);

    // pooling + losses
    k_pool_out<<<8 * NB, 128, 0, stream>>>(bufX, sarr, pool);
    k_edge_stats<<<4 * NB, 256, 0, stream>>>(sorted, gbase, sarr, numA, denA, gst);
    k_logits_losses<<<NB + 1, 256, 0, stream>>>(pool, W_post, b_post, numA, denA, gst, outF);
}

// Round 6
// 275.808 us; speedup vs baseline: 2.3230x; 1.0785x over previous
//
#include <hip/hip_runtime.h>

#define NN 32768      // total nodes
#define NP 512        // nodes per graph
#define NB 64         // graphs
#define NE 1048576    // edges
#define FIN 16
#define H 128
#define BN_EPS 1e-5f
#define EPB 4096      // edges per hist/scatterA block
#define NBLK (NE / EPB)   // 256
#define CAPH 8704     // max edges per half-graph
#define NSH 16        // BN shadow copies

typedef unsigned int u32;
typedef unsigned short u16;
typedef __attribute__((ext_vector_type(8))) short bf16x8;
typedef __attribute__((ext_vector_type(4))) float f32x4;

__device__ __forceinline__ u16 f2bf(float f) {
    u32 u = __float_as_uint(f);
    return (u16)((u + 0x7fffu + ((u >> 16) & 1u)) >> 16);
}
__device__ __forceinline__ float bfLo(u32 p) { return __uint_as_float(p << 16); }
__device__ __forceinline__ float bfHi(u32 p) { return __uint_as_float(p & 0xffff0000u); }
__device__ __forceinline__ float b2f(u16 v) { return __uint_as_float((u32)v << 16); }

// ---------------- workspace layout (bytes) ----------------
static constexpr size_t SZ_HALF   = (size_t)NN * H * 2;            // 8 MiB (bf16 act)
static constexpr size_t OFF_X     = 0;
static constexpr size_t OFF_AGG   = OFF_X + SZ_HALF;               // agg bf16 (aliases tmp)
static constexpr size_t OFF_TMP   = OFF_AGG;                       // int2 tmp (8 MiB)
static constexpr size_t OFF_SORT  = OFF_AGG + SZ_HALF;             // NE int2 (8 MiB)
static constexpr size_t OFF_OFFS  = OFF_SORT + (size_t)NE * 8;     // NN+8 ints
static constexpr size_t OFF_HISTG = OFF_OFFS + ((size_t)NN + 128) * 4;
static constexpr size_t OFF_STARTG= OFF_HISTG + (size_t)NBLK * NB * 4;
static constexpr size_t OFF_GBASE = OFF_STARTG + (size_t)NBLK * NB * 4;  // 65 ints
static constexpr size_t OFF_WT1   = OFF_GBASE + 512;               // 128*256 bf16 = 64 KiB
static constexpr size_t OFF_WT2   = OFF_WT1 + (size_t)H * 2 * H * 2;
static constexpr size_t OFF_S     = OFF_WT2 + (size_t)H * 2 * H * 2;   // NN*2 f32
static constexpr size_t OFF_GST   = OFF_S + (size_t)NN * 2 * 4;    // 3*NB f32
// --- zeroed region (one memset) ---
static constexpr size_t OFF_ZERO  = OFF_GST + 1024;
static constexpr size_t OFF_NUM   = OFF_ZERO;                      // NB f32
static constexpr size_t OFF_DEN   = OFF_NUM + 256;                 // NB f32
static constexpr size_t OFF_BN    = OFF_DEN + 256;                 // 2 layers * NSH * 2 * H f32
static constexpr size_t SZ_BNL    = (size_t)NSH * 2 * H * 4;
static constexpr size_t OFF_POOL  = OFF_BN + 2 * SZ_BNL;           // NB*2*H f32
static constexpr size_t ZERO_BYTES= (OFF_POOL + (size_t)NB * 2 * H * 4) - OFF_ZERO;

// ---------------- kernels ----------------

// fused prologue: [0,2048) x0 = nf@W_pre+b_pre ; [2048,2304) WT prep ; [2304,2560) hist
__global__ __launch_bounds__(256) void k_prep(
        const float* __restrict__ nf, const float* __restrict__ Wp,
        const float* __restrict__ bp,
        const float* __restrict__ W1_rel, const float* __restrict__ W1_root,
        const float* __restrict__ W2_rel, const float* __restrict__ W2_root,
        const int* __restrict__ src,
        u16* __restrict__ x0, u16* __restrict__ WT1, u16* __restrict__ WT2,
        int* __restrict__ histG) {
    int t = threadIdx.x, bid = blockIdx.x;
    if (bid < 2048) {                       // ---- pre: 16 nodes per block
        __shared__ float sW[FIN * H];
        __shared__ float sNF[16 * FIN];
        for (int i = t; i < FIN * H; i += 256) sW[i] = Wp[i];
        int n0 = bid * 16;
        sNF[t] = nf[n0 * FIN + t];
        __syncthreads();
        int col = t & 127, half = t >> 7;
        float b = bp[col];
        #pragma unroll
        for (int r = 0; r < 8; ++r) {
            int rr = half * 8 + r;
            float acc = b;
            #pragma unroll
            for (int f = 0; f < FIN; ++f) acc += sNF[rr * FIN + f] * sW[f * H + col];
            x0[(size_t)(n0 + rr) * H + col] = f2bf(acc);
        }
    } else if (bid < 2304) {                // ---- WT[c][k] = stacked W^T -> bf16
        int base = bid - 2048;
        const float* __restrict__ Wrel = (base < 128) ? W1_rel : W2_rel;
        const float* __restrict__ Wroot = (base < 128) ? W1_root : W2_root;
        u16* WT = (base < 128) ? WT1 : WT2;
        int i = (base & 127) * 256 + t;
        int c = i >> 8, k = i & 255;
        float v = (k < H) ? Wrel[k * H + c] : Wroot[(k - H) * H + c];
        WT[c * 256 + k] = f2bf(v);
    } else {                                // ---- per-chunk graph histogram
        __shared__ int h[NB];
        if (t < NB) h[t] = 0;
        __syncthreads();
        int ebase = (bid - 2304) * EPB;
        #pragma unroll
        for (int i = 0; i < EPB / 256; ++i) {
            int s = src[ebase + i * 256 + t];
            atomicAdd(&h[s >> 9], 1);
        }
        __syncthreads();
        if (t < NB) histG[(bid - 2304) * NB + t] = h[t];
    }
}

// scan histG -> per-(block,graph) global bases + per-graph bases. 1 block, 1024 threads.
__global__ __launch_bounds__(1024) void k_scanG(const int* __restrict__ histG,
                                                int* __restrict__ startG,
                                                int* __restrict__ gbase) {
    __shared__ int csum[16][64];
    __shared__ int gpre[64];
    int t = threadIdx.x;
    int g = t & 63, c = t >> 6;
    int vals[16];
    int s = 0;
    #pragma unroll
    for (int i = 0; i < 16; ++i) {
        vals[i] = histG[(c * 16 + i) * NB + g];
        s += vals[i];
    }
    csum[c][g] = s;
    __syncthreads();
    int pre = 0;
    for (int i = 0; i < c; ++i) pre += csum[i][g];
    if (c == 0) {
        int tot = 0;
        #pragma unroll
        for (int i = 0; i < 16; ++i) tot += csum[i][g];
        int x = tot;
        #pragma unroll
        for (int o = 1; o < 64; o <<= 1) {
            int y = __shfl_up(x, o);
            if (g >= o) x += y;
        }
        gpre[g] = x - tot;
        gbase[g] = x - tot;
        if (g == 63) gbase[64] = x;
    }
    __syncthreads();
    int run = gpre[g] + pre;
    #pragma unroll
    for (int i = 0; i < 16; ++i) {
        startG[(c * 16 + i) * NB + g] = run;
        run += vals[i];
    }
}

// LDS-staged graph-sort of each 4096-edge chunk -> coalesced writes.
__global__ __launch_bounds__(256) void k_scatterA(
        const int* __restrict__ src, const int* __restrict__ dst,
        const float* __restrict__ ew, const int* __restrict__ histG,
        const int* __restrict__ startG, int2* __restrict__ tmp) {
    __shared__ int lstart[NB + 1];
    __shared__ int cursor[NB];
    __shared__ int gdst[NB];
    __shared__ int2 buf[EPB];   // 32 KB
    int t = threadIdx.x, bid = blockIdx.x;
    if (t < NB) {
        int c = histG[bid * NB + t];
        int x = c;
        #pragma unroll
        for (int o = 1; o < 64; o <<= 1) {
            int y = __shfl_up(x, o);
            if (t >= o) x += y;
        }
        lstart[t] = x - c;
        cursor[t] = x - c;
        gdst[t] = startG[bid * NB + t];
        if (t == 63) lstart[NB] = x;  // == EPB
    }
    __syncthreads();
    int ebase = bid * EPB;
    #pragma unroll
    for (int i = 0; i < EPB / 256; ++i) {
        int e = ebase + i * 256 + t;
        int s = src[e], d = dst[e];
        float w = ew[e];
        int g = s >> 9;
        int meta = (s & 511) | ((d & 511) << 9);
        int p = atomicAdd(&cursor[g], 1);
        buf[p] = make_int2(meta, __float_as_int(w));
    }
    __syncthreads();
    // flat write-out: every lane stores every iter; 6-step LDS binary search for g(i)
    for (int i = t; i < EPB; i += 256) {
        int lo = 0;
        #pragma unroll
        for (int stp = 32; stp; stp >>= 1)
            if (lstart[lo + stp] <= i) lo += stp;
        tmp[gdst[lo] + (i - lstart[lo])] = buf[i];
    }
}

// per-graph counting sort by dst (2 blocks/graph). Emits final CSR + offs.
__global__ __launch_bounds__(512) void k_sortB(
        const int2* __restrict__ tmp, const int* __restrict__ gbase,
        int2* __restrict__ sorted, int* __restrict__ offs) {
    __shared__ int hist[NP];
    __shared__ int start[NP + 1];
    __shared__ int cursor[NP / 2];
    __shared__ int wsum[8];
    __shared__ int perm[CAPH];   // 34 KB
    int t = threadIdx.x;
    int lane = t & 63, wv = t >> 6;
    int g = blockIdx.x >> 1, half = blockIdx.x & 1;
    int gbeg = gbase[g], gend = gbase[g + 1];
    int cnt = gend - gbeg;
    hist[t] = 0;
    __syncthreads();
    for (int i = t; i < cnt; i += 512) {
        int meta = tmp[gbeg + i].x;
        atomicAdd(&hist[(meta >> 9) & 511], 1);
    }
    __syncthreads();
    // wave-shfl scan (2 barriers) instead of Hillis-Steele (18)
    int c = hist[t];
    int x = c;
    #pragma unroll
    for (int o = 1; o < 64; o <<= 1) {
        int y = __shfl_up(x, o);
        if (lane >= o) x += y;
    }
    if (lane == 63) wsum[wv] = x;
    __syncthreads();
    int off = 0;
    #pragma unroll
    for (int i = 0; i < 8; ++i) off += (i < wv) ? wsum[i] : 0;
    start[t] = off + x - c;           // exclusive prefix
    if (t == 511) start[NP] = off + x;  // == cnt
    __syncthreads();
    int h0 = half * 256;
    if (t < 256) {
        int n = h0 + t;
        offs[g * NP + n] = gbeg + start[n];
        cursor[t] = start[n];
    }
    if (blockIdx.x == 0 && t == 0) offs[NN] = NE;
    __syncthreads();
    int ha = start[h0];
    int hb = half ? cnt : start[256];
    for (int i = t; i < cnt; i += 512) {
        int meta = tmp[gbeg + i].x;
        int d = (meta >> 9) & 511;
        if ((d >> 8) == half) {
            int p = atomicAdd(&cursor[d - h0], 1);
            perm[p - ha] = i;
        }
    }
    __syncthreads();
    for (int o = ha + t; o < hb; o += 512) {
        sorted[gbeg + o] = tmp[gbeg + perm[o - ha]];
    }
}

// agg[node,:] = sum_e w_e * x[src_e,:]  (bf16 in/out, fp32 acc; 1 wave per node)
__global__ __launch_bounds__(256) void k_agg(const u16* __restrict__ x,
        const int* __restrict__ offs, const int2* __restrict__ rec,
        u16* __restrict__ agg) {
    int wv = threadIdx.x >> 6, lane = threadIdx.x & 63;
    int b = blockIdx.x;
    int swz = (b & 7) * (NN / 8 / 4) + (b >> 3);   // XCD-locality swizzle
    int node = swz * 4 + wv;
    int sbase = node & ~(NP - 1);
    const u16* xg = x + (size_t)sbase * H;
    int beg = offs[node], end = offs[node + 1];
    float a0 = 0.f, a1 = 0.f;
    int j = beg;
    for (; j + 4 <= end; j += 4) {
        int2 r0 = rec[j], r1 = rec[j + 1], r2 = rec[j + 2], r3 = rec[j + 3];
        u32 p0 = *(const u32*)(xg + (size_t)(r0.x & 511) * H + 2 * lane);
        u32 p1 = *(const u32*)(xg + (size_t)(r1.x & 511) * H + 2 * lane);
        u32 p2 = *(const u32*)(xg + (size_t)(r2.x & 511) * H + 2 * lane);
        u32 p3 = *(const u32*)(xg + (size_t)(r3.x & 511) * H + 2 * lane);
        float w0 = __int_as_float(r0.y), w1 = __int_as_float(r1.y);
        float w2 = __int_as_float(r2.y), w3 = __int_as_float(r3.y);
        a0 += w0 * bfLo(p0); a1 += w0 * bfHi(p0);
        a0 += w1 * bfLo(p1); a1 += w1 * bfHi(p1);
        a0 += w2 * bfLo(p2); a1 += w2 * bfHi(p2);
        a0 += w3 * bfLo(p3); a1 += w3 * bfHi(p3);
    }
    for (; j < end; ++j) {
        int2 r = rec[j];
        u32 p = *(const u32*)(xg + (size_t)(r.x & 511) * H + 2 * lane);
        float w = __int_as_float(r.y);
        a0 += w * bfLo(p); a1 += w * bfHi(p);
    }
    u32 packed = (u32)f2bf(a0) | ((u32)f2bf(a1) << 16);
    *(u32*)(agg + (size_t)node * H + 2 * lane) = packed;
}

// Y = [Amat|Xmat](bf16) @ WT^T(bf16) + brel via MFMA, fp32 acc. Y may alias Xmat.
__global__ __launch_bounds__(256) void k_gemm(
        const u16* __restrict__ Amat, const u16* Xmat,
        const u16* __restrict__ WT, const float* __restrict__ brel,
        u16* Y, float* __restrict__ bn_base) {
    __shared__ u16 sWT[128][264];          // [col][k], +8 pad
    __shared__ float colS[128], colQ[128];
    int tid = threadIdx.x;
    int w = tid >> 6, lane = tid & 63;
    int lr = lane & 15, lg = lane >> 4;
    int row0 = blockIdx.x * 64;
    int myrow = row0 + w * 16 + lr;

    bf16x8 af[8];
    const u16* pa = Amat + (size_t)myrow * H + lg * 8;
    const u16* px = Xmat + (size_t)myrow * H + lg * 8;
    #pragma unroll
    for (int kt = 0; kt < 4; ++kt) af[kt] = *(const bf16x8*)(pa + kt * 32);
    #pragma unroll
    for (int kt = 0; kt < 4; ++kt) af[4 + kt] = *(const bf16x8*)(px + kt * 32);

    for (int i = tid; i < 128 * 32; i += 256) {
        int r = i >> 5, c = i & 31;
        *(uint4*)&sWT[r][c * 8] = *(const uint4*)(WT + r * 256 + c * 8);
    }
    if (tid < 128) { colS[tid] = 0.f; colQ[tid] = 0.f; }
    __syncthreads();

    f32x4 acc[8];
    #pragma unroll
    for (int nt = 0; nt < 8; ++nt) acc[nt] = (f32x4){0.f, 0.f, 0.f, 0.f};

    #pragma unroll
    for (int kt = 0; kt < 8; ++kt) {
        #pragma unroll
        for (int nt = 0; nt < 8; ++nt) {
            bf16x8 bf = *(const bf16x8*)&sWT[nt * 16 + lr][kt * 32 + lg * 8];
            acc[nt] = __builtin_amdgcn_mfma_f32_16x16x32_bf16(af[kt], bf, acc[nt], 0, 0, 0);
        }
    }

    float cs[8], cq[8];
    #pragma unroll
    for (int nt = 0; nt < 8; ++nt) {
        int col = nt * 16 + lr;
        float bias = brel[col];
        float s = 0.f, q = 0.f;
        #pragma unroll
        for (int j = 0; j < 4; ++j) {
            float v = acc[nt][j] + bias;
            int row = row0 + w * 16 + lg * 4 + j;
            Y[(size_t)row * H + col] = f2bf(v);
            s += v; q += v * v;
        }
        cs[nt] = s; cq[nt] = q;
    }
    #pragma unroll
    for (int nt = 0; nt < 8; ++nt) {
        cs[nt] += __shfl_xor(cs[nt], 16); cs[nt] += __shfl_xor(cs[nt], 32);
        cq[nt] += __shfl_xor(cq[nt], 16); cq[nt] += __shfl_xor(cq[nt], 32);
    }
    if (lg == 0) {
        #pragma unroll
        for (int nt = 0; nt < 8; ++nt) {
            atomicAdd(&colS[nt * 16 + lr], cs[nt]);
            atomicAdd(&colQ[nt * 16 + lr], cq[nt]);
        }
    }
    __syncthreads();
    if (tid < 128) {
        int sh = blockIdx.x & (NSH - 1);
        atomicAdd(&bn_base[(sh * 2 + 0) * H + tid], colS[tid]);
        atomicAdd(&bn_base[(sh * 2 + 1) * H + tid], colQ[tid]);
    }
}

// BN finalize (per-block redundant shadow reduce) + ReLU apply, in-place bf16.
__global__ __launch_bounds__(256) void k_bnrelu(u16* __restrict__ y,
        const float* __restrict__ bn_base, const float* __restrict__ g,
        const float* __restrict__ be) {
    __shared__ float scL[H], shL[H];
    int t = threadIdx.x;
    if (t < H) {
        float su = 0.f, sq = 0.f;
        #pragma unroll
        for (int sh = 0; sh < NSH; ++sh) {
            su += bn_base[(sh * 2 + 0) * H + t];
            sq += bn_base[(sh * 2 + 1) * H + t];
        }
        float mu = su * (1.f / NN);
        float var = sq * (1.f / NN) - mu * mu;
        float sc = rsqrtf(var + BN_EPS) * g[t];
        scL[t] = sc;
        shL[t] = be[t] - mu * sc;
    }
    __syncthreads();
    #pragma unroll
    for (int it = 0; it < 4; ++it) {
        int idx = blockIdx.x * 1024 + it * 256 + t;
        int c = (idx & 15) * 8;
        uint4 u = ((const uint4*)y)[idx];
        u32 uu[4] = {u.x, u.y, u.z, u.w};
        u32 ro[4];
        #pragma unroll
        for (int p = 0; p < 4; ++p) {
            float v0 = fmaxf(fmaf(bfLo(uu[p]), scL[c + 2 * p], shL[c + 2 * p]), 0.f);
            float v1 = fmaxf(fmaf(bfHi(uu[p]), scL[c + 2 * p + 1], shL[c + 2 * p + 1]), 0.f);
            ro[p] = (u32)f2bf(v0) | ((u32)f2bf(v1) << 16);
        }
        uint4 o; o.x = ro[0]; o.y = ro[1]; o.z = ro[2]; o.w = ro[3];
        ((uint4*)y)[idx] = o;
    }
}

// layer 2: BN finalize + ReLU + s = softmax(x @ W_pool + b_pool)
__global__ __launch_bounds__(256) void k_bnrelu_s(u16* __restrict__ y,
        const float* __restrict__ bn_base, const float* __restrict__ g,
        const float* __restrict__ be, const float* __restrict__ Wp,
        const float* __restrict__ bp, float* __restrict__ s) {
    __shared__ float scL[H], shL[H];
    int t = threadIdx.x;
    if (t < H) {
        float su = 0.f, sq = 0.f;
        #pragma unroll
        for (int sh = 0; sh < NSH; ++sh) {
            su += bn_base[(sh * 2 + 0) * H + t];
            sq += bn_base[(sh * 2 + 1) * H + t];
        }
        float mu = su * (1.f / NN);
        float var = sq * (1.f / NN) - mu * mu;
        float sc = rsqrtf(var + BN_EPS) * g[t];
        scL[t] = sc;
        shL[t] = be[t] - mu * sc;
    }
    __syncthreads();
    #pragma unroll
    for (int it = 0; it < 4; ++it) {
        int idx = blockIdx.x * 1024 + it * 256 + t;
        int c = (idx & 15) * 8;
        uint4 u = ((const uint4*)y)[idx];
        u32 uu[4] = {u.x, u.y, u.z, u.w};
        u32 ro[4];
        float z0 = 0.f, z1 = 0.f;
        #pragma unroll
        for (int p = 0; p < 4; ++p) {
            float v0 = fmaxf(fmaf(bfLo(uu[p]), scL[c + 2 * p], shL[c + 2 * p]), 0.f);
            float v1 = fmaxf(fmaf(bfHi(uu[p]), scL[c + 2 * p + 1], shL[c + 2 * p + 1]), 0.f);
            ro[p] = (u32)f2bf(v0) | ((u32)f2bf(v1) << 16);
            z0 += v0 * Wp[(c + 2 * p) * 2] + v1 * Wp[(c + 2 * p + 1) * 2];
            z1 += v0 * Wp[(c + 2 * p) * 2 + 1] + v1 * Wp[(c + 2 * p + 1) * 2 + 1];
        }
        uint4 o; o.x = ro[0]; o.y = ro[1]; o.z = ro[2]; o.w = ro[3];
        ((uint4*)y)[idx] = o;
        #pragma unroll
        for (int off = 8; off; off >>= 1) {
            z0 += __shfl_down(z0, off);
            z1 += __shfl_down(z1, off);
        }
        if ((t & 15) == 0) {
            int row = idx >> 4;
            z0 += bp[0]; z1 += bp[1];
            float m = fmaxf(z0, z1);
            float e0 = expf(z0 - m), e1 = expf(z1 - m);
            float inv = 1.f / (e0 + e1);
            s[row * 2] = e0 * inv;
            s[row * 2 + 1] = e1 * inv;
        }
    }
}

// fused: [0,256) pool accumulation ; [256,512) edge stats + graph stats
__global__ __launch_bounds__(256) void k_pool_edge(
        const u16* __restrict__ x, const float* __restrict__ s,
        const int2* __restrict__ sorted, const int* __restrict__ gbase,
        float* __restrict__ pool, float* __restrict__ num,
        float* __restrict__ den, float* __restrict__ gst) {
    int bid = blockIdx.x, t = threadIdx.x;
    if (bid < 256) {   // ---- pool: graph b, 128-node chunk, 2 subs of 64 nodes
        int b = bid & 63, chunk = bid >> 6;
        int h = t & 127, sub = t >> 7;
        int n0 = b * NP + chunk * 128 + sub * 64;
        float a0 = 0.f, a1 = 0.f;
        for (int i = 0; i < 64; ++i) {
            float2 sv = ((const float2*)s)[n0 + i];
            float xv = b2f(x[(size_t)(n0 + i) * H + h]);
            a0 += sv.x * xv;
            a1 += sv.y * xv;
        }
        atomicAdd(&pool[(b * 2 + 0) * H + h], a0);
        atomicAdd(&pool[(b * 2 + 1) * H + h], a1);
    } else {           // ---- edge stats
        __shared__ float2 sl[NP];
        __shared__ float ln[4], ld2[4];
        int ebid = bid - 256;
        int g = ebid >> 2, q = ebid & 3;
        int gbeg = gbase[g], gend = gbase[g + 1];
        for (int i = t; i < NP; i += 256) sl[i] = ((const float2*)s)[g * NP + i];
        __syncthreads();
        float an = 0.f, ad = 0.f;
        int cnt = gend - gbeg;
        int q0 = gbeg + (cnt * q) / 4, q1 = gbeg + (cnt * (q + 1)) / 4;
        for (int i = q0 + t; i < q1; i += 256) {
            int2 r = sorted[i];
            float w = __int_as_float(r.y);
            float2 ss = sl[r.x & 511];
            float2 sd = sl[(r.x >> 9) & 511];
            an += w * (ss.x * sd.x + ss.y * sd.y);
            ad += w * (ss.x * ss.x + ss.y * ss.y);
        }
        for (int o = 32; o; o >>= 1) { an += __shfl_down(an, o); ad += __shfl_down(ad, o); }
        if ((t & 63) == 0) { ln[t >> 6] = an; ld2[t >> 6] = ad; }
        __syncthreads();
        if (t == 0) {
            atomicAdd(&num[g], ln[0] + ln[1] + ln[2] + ln[3]);
            atomicAdd(&den[g], ld2[0] + ld2[1] + ld2[2] + ld2[3]);
        }
        if (q == 0) {
            float p00 = 0.f, p01 = 0.f, p11 = 0.f;
            for (int i = t; i < NP; i += 256) {
                float2 sv = sl[i];
                p00 += sv.x * sv.x;
                p01 += sv.x * sv.y;
                p11 += sv.y * sv.y;
            }
            for (int o = 32; o; o >>= 1) {
                p00 += __shfl_down(p00, o);
                p01 += __shfl_down(p01, o);
                p11 += __shfl_down(p11, o);
            }
            __shared__ float tp[3][4];
            if ((t & 63) == 0) {
                int w = t >> 6;
                tp[0][w] = p00; tp[1][w] = p01; tp[2][w] = p11;
            }
            __syncthreads();
            if (t == 0) {
                gst[g] = tp[0][0] + tp[0][1] + tp[0][2] + tp[0][3];
                gst[NB + g] = tp[1][0] + tp[1][1] + tp[1][2] + tp[1][3];
                gst[2 * NB + g] = tp[2][0] + tp[2][1] + tp[2][2] + tp[2][3];
            }
        }
    }
}

// bid<64: logits for graph bid ; bid==64: losses
__global__ void k_logits_losses(const float* __restrict__ pool, const float* __restrict__ Wpost,
                                const float* __restrict__ bpost, const float* __restrict__ num,
                                const float* __restrict__ den, const float* __restrict__ gst,
                                float* __restrict__ out) {
    int t = threadIdx.x;
    if (blockIdx.x < 64) {
        int b = blockIdx.x;
        float v = pool[b * 256 + t];
        v = v > 0.f ? v : 0.f;
        float p0 = v * Wpost[t * 2], p1 = v * Wpost[t * 2 + 1];
        for (int o = 32; o; o >>= 1) { p0 += __shfl_down(p0, o); p1 += __shfl_down(p1, o); }
        __shared__ float t0[4], t1[4];
        if ((t & 63) == 0) { t0[t >> 6] = p0; t1[t >> 6] = p1; }
        __syncthreads();
        if (t == 0) {
            out[b * 2] = t0[0] + t0[1] + t0[2] + t0[3] + bpost[0];
            out[b * 2 + 1] = t1[0] + t1[1] + t1[2] + t1[3] + bpost[1];
        }
    } else if (t < 64) {
        float s00 = gst[t], s01 = gst[NB + t], s11 = gst[2 * NB + t];
        float mc = -(num[t] / den[t]);
        float nrm = sqrtf(s00 * s00 + 2.f * s01 * s01 + s11 * s11);
        const float a = 0.70710678118654752440f;
        float d00 = s00 / nrm - a, d01 = s01 / nrm, d11 = s11 / nrm - a;
        float ol = sqrtf(d00 * d00 + 2.f * d01 * d01 + d11 * d11);
        for (int o = 32; o; o >>= 1) { mc += __shfl_down(mc, o); ol += __shfl_down(ol, o); }
        if (t == 0) {
            out[NB * 2] = mc * (1.f / NB);
            out[NB * 2 + 1] = ol * (1.f / NB);
        }
    }
}

// ---------------- launch ----------------
extern "C" void kernel_launch(void* const* d_in, const int* in_sizes, int n_in,
                              void* d_out, int out_size, void* d_ws, size_t ws_size,
                              hipStream_t stream) {
    const float* nf     = (const float*)d_in[0];
    const int*   ei     = (const int*)d_in[1];
    const float* ew     = (const float*)d_in[2];
    const float* W_pre  = (const float*)d_in[4];
    const float* b_pre  = (const float*)d_in[5];
    const float* W1_rel = (const float*)d_in[6];
    const float* b1_rel = (const float*)d_in[7];
    const float* W1_root= (const float*)d_in[8];
    const float* g1     = (const float*)d_in[9];
    const float* be1    = (const float*)d_in[10];
    const float* W2_rel = (const float*)d_in[11];
    const float* b2_rel = (const float*)d_in[12];
    const float* W2_root= (const float*)d_in[13];
    const float* g2     = (const float*)d_in[14];
    const float* be2    = (const float*)d_in[15];
    const float* W_pool = (const float*)d_in[16];
    const float* b_pool = (const float*)d_in[17];
    const float* W_post = (const float*)d_in[18];
    const float* b_post = (const float*)d_in[19];

    char* ws = (char*)d_ws;
    u16*   bufX   = (u16*)(ws + OFF_X);
    u16*   bufAgg = (u16*)(ws + OFF_AGG);
    int2*  tmp    = (int2*)(ws + OFF_TMP);
    int2*  sorted = (int2*)(ws + OFF_SORT);
    int*   offs   = (int*)(ws + OFF_OFFS);
    int*   histG  = (int*)(ws + OFF_HISTG);
    int*   startG = (int*)(ws + OFF_STARTG);
    int*   gbase  = (int*)(ws + OFF_GBASE);
    u16*   WT1    = (u16*)(ws + OFF_WT1);
    u16*   WT2    = (u16*)(ws + OFF_WT2);
    float* sarr   = (float*)(ws + OFF_S);
    float* gst    = (float*)(ws + OFF_GST);
    float* numA   = (float*)(ws + OFF_NUM);
    float* denA   = (float*)(ws + OFF_DEN);
    float* bn     = (float*)(ws + OFF_BN);
    float* pool   = (float*)(ws + OFF_POOL);
    float* outF   = (float*)d_out;

    const int* srcA = ei;
    const int* dstA = ei + NE;
    float* bn1 = bn;
    float* bn2 = (float*)(ws + OFF_BN + SZ_BNL);

    hipMemsetAsync(ws + OFF_ZERO, 0, ZERO_BYTES, stream);

    k_prep<<<2560, 256, 0, stream>>>(nf, W_pre, b_pre, W1_rel, W1_root,
                                     W2_rel, W2_root, srcA, bufX, WT1, WT2, histG);
    k_scanG<<<1, 1024, 0, stream>>>(histG, startG, gbase);
    k_scatterA<<<NBLK, 256, 0, stream>>>(srcA, dstA, ew, histG, startG, tmp);
    k_sortB<<<2 * NB, 512, 0, stream>>>(tmp, gbase, sorted, offs);

    // layer 1
    k_agg<<<NN / 4, 256, 0, stream>>>(bufX, offs, sorted, bufAgg);
    k_gemm<<<NN / 64, 256, 0, stream>>>(bufAgg, bufX, WT1, b1_rel, bufX, bn1);
    k_bnrelu<<<512, 256, 0, stream>>>(bufX, bn1, g1, be1);

    // layer 2
    k_agg<<<NN / 4, 256, 0, stream>>>(bufX, offs, sorted, bufAgg);
    k_gemm<<<NN / 64, 256, 0, stream>>>(bufAgg, bufX, WT2, b2_rel, bufX, bn2);
    k_bnrelu_s<<<512, 256, 0, stream>>>(bufX, bn2, g2, be2, W_pool, b_pool, sarr);

    // pooling + losses
    k_pool_edge<<<512, 256, 0, stream>>>(bufX, sarr, sorted, gbase, pool, numA, denA, gst);
    k_logits_losses<<<NB + 1, 256, 0, stream>>>(pool, W_post, b_post, numA, denA, gst, outF);
}